// Round 7
// baseline (211.230 us; speedup 1.0000x reference)
//
#include <hip/hip_runtime.h>
#include <hip/hip_bf16.h>
#include <stdint.h>

#define Bv 2
#define Nv 1000
#define Ev 2000
#define Hv 128
#define Mv 4000  // Bv*Ev

typedef __attribute__((ext_vector_type(8))) short bf16x8;
typedef __attribute__((ext_vector_type(4))) float f32x4;
typedef unsigned short u16;
typedef unsigned int u32;

static __device__ __forceinline__ u32 pack2bf(float a, float b) {
  union { __hip_bfloat162 h; u32 u; } c;
  c.h = __float22bfloat162_rn(make_float2(a, b));
  return c.u;
}
static __device__ __forceinline__ u16 cvt1bf(float a) {
  return (u16)(pack2bf(a, 0.f) & 0xffffu);
}

// edge_network fp32 [H][H][H] -> bf16, same (h,i,j) layout. 2M elems, 8/thread.
__global__ void k_cvt_en(const float* __restrict__ en, u16* __restrict__ enbf) {
  size_t idx = ((size_t)blockIdx.x * 256u + threadIdx.x) * 8u;
  const f32x4* p = (const f32x4*)(en + idx);
  f32x4 a = p[0], b = p[1];
  uint4 o;
  o.x = pack2bf(a.x, a.y);
  o.y = pack2bf(a.z, a.w);
  o.z = pack2bf(b.x, b.y);
  o.w = pack2bf(b.z, b.w);
  *(uint4*)(enbf + idx) = o;
}

// Transpose+convert: src fp32 [R][C] -> dst bf16 [C][Rpad], zero-filled rows R..Rpad.
__global__ void k_tr_cvt(const float* __restrict__ src, u16* __restrict__ dst,
                         int R, int C, int Rpad) {
  __shared__ float tile[32][33];
  const int z = blockIdx.z;
  src += (size_t)z * R * C;
  dst += (size_t)z * C * Rpad;
  const int r0 = blockIdx.x * 32, c0 = blockIdx.y * 32;
  const int tx = threadIdx.x & 31, ty = threadIdx.x >> 5;
#pragma unroll
  for (int rr = 0; rr < 4; ++rr) {
    int r = r0 + ty + rr * 8;
    int c = c0 + tx;
    float v = (r < R && c < C) ? src[(size_t)r * C + c] : 0.f;
    tile[ty + rr * 8][tx] = v;
  }
  __syncthreads();
#pragma unroll
  for (int rr = 0; rr < 4; ++rr) {
    int oc = c0 + ty + rr * 8;  // dst row = src col
    int orr = r0 + tx;          // dst col = src row
    if (oc < C)
      dst[(size_t)oc * Rpad + orr] = cvt1bf(tile[tx][ty + rr * 8]);
  }
}

// Straight fp32 -> bf16 convert (no transpose). 8 elems/thread.
__global__ void k_cvt(const float* __restrict__ src, u16* __restrict__ dst) {
  size_t idx = ((size_t)blockIdx.x * 256u + threadIdx.x) * 8u;
  const f32x4* p = (const f32x4*)(src + idx);
  f32x4 a = p[0], b = p[1];
  uint4 o;
  o.x = pack2bf(a.x, a.y);
  o.y = pack2bf(a.z, a.w);
  o.z = pack2bf(b.x, b.y);
  o.w = pack2bf(b.z, b.w);
  *(uint4*)(dst + idx) = o;
}

// Split-K GEMM partial: Cacc[m,i] += sum_{k in chunk} A[m,k]*BT[i,k]
template <int M, int KREAL, int KPAD, bool ROWSUM>
__launch_bounds__(256, 4)
__global__ void k_gemm_split(const float* __restrict__ A, const u16* __restrict__ BT,
                             float* __restrict__ Cacc, float* __restrict__ nrmacc) {
  __shared__ u16 AL[64 * 136];
  __shared__ float rowsum[64];
  const int b = blockIdx.z;
  A    += (size_t)b * M * KREAL;
  BT   += (size_t)b * 128 * KPAD;
  Cacc += (size_t)b * M * 128;
  if (ROWSUM) nrmacc += (size_t)b * M;
  const int t = threadIdx.x;
  const int lane = t & 63;
  const int w = t >> 6;
  const int row16 = lane & 15;
  const int kg = lane >> 4;
  const int mrow0 = blockIdx.x * 64;
  const int kc = blockIdx.y * 128;
  const int mtg = (w >> 1) * 2;
  const int itg = (w & 1) * 4;
  f32x4 acc[2][4];
#pragma unroll
  for (int i = 0; i < 2; ++i)
#pragma unroll
    for (int j = 0; j < 4; ++j) acc[i][j] = (f32x4){0.f, 0.f, 0.f, 0.f};
  if (ROWSUM && t < 64) rowsum[t] = 0.f;
  __syncthreads();
#pragma unroll
  for (int r = 0; r < 4; ++r) {
    const int chunk = t + r * 256;
    const int m = chunk >> 4;
    const int jc = (chunk & 15) * 8;
    const int gm = mrow0 + m;
    const int gk = kc + jc;
    f32x4 x0 = {0.f, 0.f, 0.f, 0.f}, x1 = {0.f, 0.f, 0.f, 0.f};
    if (gm < M && gk + 8 <= KREAL) {
      const f32x4* p = (const f32x4*)(A + (size_t)gm * KREAL + gk);
      x0 = p[0];
      x1 = p[1];
    }
    if (ROWSUM) {
      float s8 = x0.x + x0.y + x0.z + x0.w + x1.x + x1.y + x1.z + x1.w;
      s8 += __shfl_down(s8, 8, 16);
      s8 += __shfl_down(s8, 4, 16);
      s8 += __shfl_down(s8, 2, 16);
      s8 += __shfl_down(s8, 1, 16);
      if ((lane & 15) == 0) rowsum[m] += s8;
    }
    uint4 o;
    o.x = pack2bf(x0.x, x0.y);
    o.y = pack2bf(x0.z, x0.w);
    o.z = pack2bf(x1.x, x1.y);
    o.w = pack2bf(x1.z, x1.w);
    *(uint4*)&AL[m * 136 + jc] = o;
  }
  __syncthreads();
#pragma unroll
  for (int kk = 0; kk < 4; ++kk) {
    bf16x8 a[2], bfr[4];
#pragma unroll
    for (int q = 0; q < 2; ++q)
      a[q] = *(const bf16x8*)&AL[((mtg + q) * 16 + row16) * 136 + kk * 32 + kg * 8];
#pragma unroll
    for (int q = 0; q < 4; ++q)
      bfr[q] = *(const bf16x8*)(BT + (size_t)((itg + q) * 16 + row16) * KPAD + kc + kk * 32 + kg * 8);
#pragma unroll
    for (int mi = 0; mi < 2; ++mi)
#pragma unroll
      for (int ii = 0; ii < 4; ++ii)
        acc[mi][ii] = __builtin_amdgcn_mfma_f32_16x16x32_bf16(a[mi], bfr[ii], acc[mi][ii], 0, 0, 0);
  }
  if (ROWSUM && t < 64 && mrow0 + t < M) atomicAdd(&nrmacc[mrow0 + t], rowsum[t]);
#pragma unroll
  for (int mi = 0; mi < 2; ++mi) {
#pragma unroll
    for (int r = 0; r < 4; ++r) {
      const int lrow = (mtg + mi) * 16 + kg * 4 + r;
      const int gm = mrow0 + lrow;
      if (gm < M) {
#pragma unroll
        for (int ii = 0; ii < 4; ++ii)
          atomicAdd(&Cacc[(size_t)gm * 128 + (itg + ii) * 16 + row16], acc[mi][ii][r]);
      }
    }
  }
}

// out = (aggacc + ns) / (norm + 1)
__global__ void k_epi(const float* __restrict__ acc, const float* __restrict__ ns,
                      const float* __restrict__ nrm, float* __restrict__ out) {
  const int idx = (blockIdx.x * 256 + threadIdx.x) * 4;
  f32x4 a = *(const f32x4*)(acc + idx);
  f32x4 s = *(const f32x4*)(ns + idx);
  const int row = idx >> 7;
  float inv = 1.f / (nrm[row] + 1.0f);
  *(f32x4*)(out + idx) = (a + s) * inv;
}

// v5: same dataflow as v4 (swapped operands, reg B-frags, barrier-free h-loop,
// reg-double-buffered A) but 8 waves/block x 16 i each -> 4 waves/SIMD of TLP.
// neweI[b][i][m] += sum_{h in grp} ev[m,h] * (EN[h] @ emb^T)[i,m]
// Grid (32 mt, 8 hg, 2 b) = 512 blocks, 512 thr.
__launch_bounds__(512, 4)
__global__ void k_edge_mix(const float* __restrict__ ev, const float* __restrict__ emb,
                           const u16* __restrict__ enbf, float* __restrict__ neweI) {
  __shared__ float EVL[64 * 20];  // ev slice [64 m][16 h], stride 20
  const int t = threadIdx.x;
  const int lane = t & 63;
  const int w = t >> 6;           // 8 waves
  const int row16 = lane & 15;
  const int kg = lane >> 4;
  const int b = blockIdx.z;
  const int mt = blockIdx.x;
  const int h0 = blockIdx.y * 16;
  const int mbase = mt * 64;

  // stage ev slice once
  if (t < 64) {
    const int ml = mbase + t;
    const float* src = ev + ((size_t)b * Ev + ml) * Hv + h0;
    const f32x4 z = {0.f, 0.f, 0.f, 0.f};
#pragma unroll
    for (int q = 0; q < 4; ++q) {
      f32x4 v = (ml < Ev) ? *(const f32x4*)(src + q * 4) : z;
      *(f32x4*)&EVL[t * 20 + q * 4] = v;
    }
  }

  // B-frags once per wave: emb[mbase + mf*16 + row16][kk*32 + kg*8 ..+8] -> bf16 regs
  bf16x8 bfrag[4][4];
#pragma unroll
  for (int mf = 0; mf < 4; ++mf) {
    const int ml = mbase + mf * 16 + row16;
    const float* src = emb + ((size_t)b * Ev + ml) * Hv;
#pragma unroll
    for (int kk = 0; kk < 4; ++kk) {
      f32x4 x0 = {0.f, 0.f, 0.f, 0.f}, x1 = {0.f, 0.f, 0.f, 0.f};
      if (ml < Ev) {
        const f32x4* p = (const f32x4*)(src + kk * 32 + kg * 8);
        x0 = p[0];
        x1 = p[1];
      }
      union { bf16x8 v; uint4 u; } c;
      c.u.x = pack2bf(x0.x, x0.y);
      c.u.y = pack2bf(x0.z, x0.w);
      c.u.z = pack2bf(x1.x, x1.y);
      c.u.w = pack2bf(x1.z, x1.w);
      bfrag[mf][kk] = c.v;
    }
  }
  __syncthreads();

  const f32x4 zero4 = {0.f, 0.f, 0.f, 0.f};
  f32x4 pers[4];
#pragma unroll
  for (int mf = 0; mf < 4; ++mf) pers[mf] = zero4;

  const int irow0 = w * 16 + row16;  // wave's 16 i-rows
  const int kcol = kg * 8;

  auto LDA = [&](int hh, bf16x8 a[4]) {
    const u16* __restrict__ bh = enbf + (size_t)(h0 + hh) * 16384;
#pragma unroll
    for (int kk = 0; kk < 4; ++kk)
      a[kk] = *(const bf16x8*)(bh + (size_t)irow0 * 128 + kk * 32 + kcol);
  };
  auto STEP = [&](int hh, bf16x8 a[4]) {
    f32x4 q[4];
#pragma unroll
    for (int mf = 0; mf < 4; ++mf)
      q[mf] = __builtin_amdgcn_mfma_f32_16x16x32_bf16(a[0], bfrag[mf][0], zero4, 0, 0, 0);
#pragma unroll
    for (int kk = 1; kk < 4; ++kk)
#pragma unroll
      for (int mf = 0; mf < 4; ++mf)
        q[mf] = __builtin_amdgcn_mfma_f32_16x16x32_bf16(a[kk], bfrag[mf][kk], q[mf], 0, 0, 0);
    float evv[4];
#pragma unroll
    for (int mf = 0; mf < 4; ++mf)
      evv[mf] = EVL[(mf * 16 + row16) * 20 + hh];
#pragma unroll
    for (int mf = 0; mf < 4; ++mf)
      pers[mf] += evv[mf] * q[mf];
  };

  bf16x8 aA[4], aB[4];
  LDA(0, aA);
#pragma unroll 1
  for (int hh = 0; hh < 16; hh += 2) {
    LDA(hh + 1, aB);   // issue next loads before consuming aA
    STEP(hh, aA);
    if (hh + 2 < 16) LDA(hh + 2, aA);
    STEP(hh + 1, aB);
  }

  // atomic fold into neweI[b][i][m] (i-major = agg GEMM's B^T layout)
#pragma unroll
  for (int mf = 0; mf < 4; ++mf) {
    const int ml = mbase + mf * 16 + row16;
    if (ml < Ev) {
#pragma unroll
      for (int r = 0; r < 4; ++r) {
        const int irow = w * 16 + kg * 4 + r;
        atomicAdd(&neweI[((size_t)b * 128 + irow) * 2048 + ml], pers[mf][r]);
      }
    }
  }
}

extern "C" void kernel_launch(void* const* d_in, const int* in_sizes, int n_in,
                              void* d_out, int out_size, void* d_ws, size_t ws_size,
                              hipStream_t stream) {
  const float* ns  = (const float*)d_in[0];  // node_state  [B][N][H]
  const float* ev  = (const float*)d_in[1];  // edge_vec    [B][E][H]
  const float* n2e = (const float*)d_in[2];  // node2edge   [B][E][N]
  const float* e2n = (const float*)d_in[3];  // edge2node   [B][N][E]
  const float* en  = (const float*)d_in[4];  // edge_network[H][H][H]
  float* out = (float*)d_out;

  char* ws = (char*)d_ws;
  float* embacc  = (float*)(ws);              // [4000][128] f32, 2,048,000 — dead after edge_mix
  float* normacc = (float*)(ws + 2048000);    // [2][1000] f32 (+pad), 8,192
  float* neweI   = (float*)(ws + 2056192);    // [2][128][2048] f32, 2,097,152 (i-major)
  u16*   nsT     = (u16*)  (ws + 2056192);    // [2][128][1024] bf16, 524,288 — overlays neweI early
  u16*   enbf    = (u16*)  (ws + 4153344);    // [128][128][128] bf16, 4,194,304 — dead after edge_mix
  float* aggacc  = (float*)(ws + 4153344);    // [2][1000][128] f32, 1,024,000 — overlays enbf late
  u16*   neweT   = (u16*)  (ws);              // [2][128][2048] bf16, 1,048,576 — overlays embacc late

  hipMemsetAsync(ws, 0, 2056192, stream);                 // zero embacc + normacc
  k_cvt_en <<<dim3(1024),     dim3(256), 0, stream>>>(en, enbf);
  k_tr_cvt <<<dim3(32, 4, 2), dim3(256), 0, stream>>>(ns, nsT, Nv, Hv, 1024);
  k_gemm_split<2000, 1000, 1024, false><<<dim3(32, 8, 2), dim3(256), 0, stream>>>(n2e, nsT, embacc, nullptr);
  hipMemsetAsync(neweI, 0, 2097152, stream);              // nsT dead now
  k_edge_mix<<<dim3(32, 8, 2), dim3(512), 0, stream>>>(ev, embacc, enbf, neweI);
  hipMemsetAsync(aggacc, 0, 1024000, stream);             // enbf dead now
  k_cvt<<<dim3(256), dim3(256), 0, stream>>>(neweI, neweT);  // embacc dead now
  k_gemm_split<1000, 2000, 2048, true><<<dim3(16, 16, 2), dim3(256), 0, stream>>>(e2n, neweT, aggacc, normacc);
  k_epi<<<dim3(250), dim3(256), 0, stream>>>(aggacc, ns, normacc, out);
}

// Round 8
// 129.665 us; speedup vs baseline: 1.6290x; 1.6290x over previous
//
#include <hip/hip_runtime.h>
#include <hip/hip_bf16.h>
#include <stdint.h>

#define Bv 2
#define Nv 1000
#define Ev 2000
#define Hv 128
#define Mv 4000  // Bv*Ev

typedef __attribute__((ext_vector_type(8))) short bf16x8;
typedef __attribute__((ext_vector_type(4))) float f32x4;
typedef unsigned short u16;
typedef unsigned int u32;

static __device__ __forceinline__ u32 pack2bf(float a, float b) {
  union { __hip_bfloat162 h; u32 u; } c;
  c.h = __float22bfloat162_rn(make_float2(a, b));
  return c.u;
}
static __device__ __forceinline__ u16 cvt1bf(float a) {
  return (u16)(pack2bf(a, 0.f) & 0xffffu);
}

// edge_network fp32 [H][H][H] -> bf16, same (h,i,j) layout. 2M elems, 8/thread.
__global__ void k_cvt_en(const float* __restrict__ en, u16* __restrict__ enbf) {
  size_t idx = ((size_t)blockIdx.x * 256u + threadIdx.x) * 8u;
  const f32x4* p = (const f32x4*)(en + idx);
  f32x4 a = p[0], b = p[1];
  uint4 o;
  o.x = pack2bf(a.x, a.y);
  o.y = pack2bf(a.z, a.w);
  o.z = pack2bf(b.x, b.y);
  o.w = pack2bf(b.z, b.w);
  *(uint4*)(enbf + idx) = o;
}

// Transpose+convert: src fp32 [R][C] -> dst bf16 [C][Rpad], zero-filled rows R..Rpad.
__global__ void k_tr_cvt(const float* __restrict__ src, u16* __restrict__ dst,
                         int R, int C, int Rpad) {
  __shared__ float tile[32][33];
  const int z = blockIdx.z;
  src += (size_t)z * R * C;
  dst += (size_t)z * C * Rpad;
  const int r0 = blockIdx.x * 32, c0 = blockIdx.y * 32;
  const int tx = threadIdx.x & 31, ty = threadIdx.x >> 5;
#pragma unroll
  for (int rr = 0; rr < 4; ++rr) {
    int r = r0 + ty + rr * 8;
    int c = c0 + tx;
    float v = (r < R && c < C) ? src[(size_t)r * C + c] : 0.f;
    tile[ty + rr * 8][tx] = v;
  }
  __syncthreads();
#pragma unroll
  for (int rr = 0; rr < 4; ++rr) {
    int oc = c0 + ty + rr * 8;  // dst row = src col
    int orr = r0 + tx;          // dst col = src row
    if (oc < C)
      dst[(size_t)oc * Rpad + orr] = cvt1bf(tile[tx][ty + rr * 8]);
  }
}

// Straight fp32 -> bf16 convert (no transpose). 8 elems/thread.
__global__ void k_cvt(const float* __restrict__ src, u16* __restrict__ dst) {
  size_t idx = ((size_t)blockIdx.x * 256u + threadIdx.x) * 8u;
  const f32x4* p = (const f32x4*)(src + idx);
  f32x4 a = p[0], b = p[1];
  uint4 o;
  o.x = pack2bf(a.x, a.y);
  o.y = pack2bf(a.z, a.w);
  o.z = pack2bf(b.x, b.y);
  o.w = pack2bf(b.z, b.w);
  *(uint4*)(dst + idx) = o;
}

// Split-K GEMM partial: Cacc[m,i] += sum_{k in chunk} A[m,k]*BT[i,k]
template <int M, int KREAL, int KPAD, bool ROWSUM>
__launch_bounds__(256, 4)
__global__ void k_gemm_split(const float* __restrict__ A, const u16* __restrict__ BT,
                             float* __restrict__ Cacc, float* __restrict__ nrmacc) {
  __shared__ u16 AL[64 * 136];
  __shared__ float rowsum[64];
  const int b = blockIdx.z;
  A    += (size_t)b * M * KREAL;
  BT   += (size_t)b * 128 * KPAD;
  Cacc += (size_t)b * M * 128;
  if (ROWSUM) nrmacc += (size_t)b * M;
  const int t = threadIdx.x;
  const int lane = t & 63;
  const int w = t >> 6;
  const int row16 = lane & 15;
  const int kg = lane >> 4;
  const int mrow0 = blockIdx.x * 64;
  const int kc = blockIdx.y * 128;
  const int mtg = (w >> 1) * 2;
  const int itg = (w & 1) * 4;
  f32x4 acc[2][4];
#pragma unroll
  for (int i = 0; i < 2; ++i)
#pragma unroll
    for (int j = 0; j < 4; ++j) acc[i][j] = (f32x4){0.f, 0.f, 0.f, 0.f};
  if (ROWSUM && t < 64) rowsum[t] = 0.f;
  __syncthreads();
#pragma unroll
  for (int r = 0; r < 4; ++r) {
    const int chunk = t + r * 256;
    const int m = chunk >> 4;
    const int jc = (chunk & 15) * 8;
    const int gm = mrow0 + m;
    const int gk = kc + jc;
    f32x4 x0 = {0.f, 0.f, 0.f, 0.f}, x1 = {0.f, 0.f, 0.f, 0.f};
    if (gm < M && gk + 8 <= KREAL) {
      const f32x4* p = (const f32x4*)(A + (size_t)gm * KREAL + gk);
      x0 = p[0];
      x1 = p[1];
    }
    if (ROWSUM) {
      float s8 = x0.x + x0.y + x0.z + x0.w + x1.x + x1.y + x1.z + x1.w;
      s8 += __shfl_down(s8, 8, 16);
      s8 += __shfl_down(s8, 4, 16);
      s8 += __shfl_down(s8, 2, 16);
      s8 += __shfl_down(s8, 1, 16);
      if ((lane & 15) == 0) rowsum[m] += s8;
    }
    uint4 o;
    o.x = pack2bf(x0.x, x0.y);
    o.y = pack2bf(x0.z, x0.w);
    o.z = pack2bf(x1.x, x1.y);
    o.w = pack2bf(x1.z, x1.w);
    *(uint4*)&AL[m * 136 + jc] = o;
  }
  __syncthreads();
#pragma unroll
  for (int kk = 0; kk < 4; ++kk) {
    bf16x8 a[2], bfr[4];
#pragma unroll
    for (int q = 0; q < 2; ++q)
      a[q] = *(const bf16x8*)&AL[((mtg + q) * 16 + row16) * 136 + kk * 32 + kg * 8];
#pragma unroll
    for (int q = 0; q < 4; ++q)
      bfr[q] = *(const bf16x8*)(BT + (size_t)((itg + q) * 16 + row16) * KPAD + kc + kk * 32 + kg * 8);
#pragma unroll
    for (int mi = 0; mi < 2; ++mi)
#pragma unroll
      for (int ii = 0; ii < 4; ++ii)
        acc[mi][ii] = __builtin_amdgcn_mfma_f32_16x16x32_bf16(a[mi], bfr[ii], acc[mi][ii], 0, 0, 0);
  }
  if (ROWSUM && t < 64 && mrow0 + t < M) atomicAdd(&nrmacc[mrow0 + t], rowsum[t]);
#pragma unroll
  for (int mi = 0; mi < 2; ++mi) {
#pragma unroll
    for (int r = 0; r < 4; ++r) {
      const int lrow = (mtg + mi) * 16 + kg * 4 + r;
      const int gm = mrow0 + lrow;
      if (gm < M) {
#pragma unroll
        for (int ii = 0; ii < 4; ++ii)
          atomicAdd(&Cacc[(size_t)gm * 128 + (itg + ii) * 16 + row16], acc[mi][ii][r]);
      }
    }
  }
}

// out = (aggacc + ns) / (norm + 1)
__global__ void k_epi(const float* __restrict__ acc, const float* __restrict__ ns,
                      const float* __restrict__ nrm, float* __restrict__ out) {
  const int idx = (blockIdx.x * 256 + threadIdx.x) * 4;
  f32x4 a = *(const f32x4*)(acc + idx);
  f32x4 s = *(const f32x4*)(ns + idx);
  const int row = idx >> 7;
  float inv = 1.f / (nrm[row] + 1.0f);
  *(f32x4*)(out + idx) = (a + s) * inv;
}

// v6: round-6 body (256 thr, 4 waves, 32 i/wave, reg dbuf A) with 8 h per block
// and doubled grid -> 4 blocks/CU resident (VGPR ~120 allows 4 waves/SIMD).
// neweI[b][i][m] += sum_{h in grp} ev[m,h] * (EN[h] @ emb^T)[i,m]
// Grid (32 mt, 16 hg, 2 b) = 1024 blocks, 256 thr.
__launch_bounds__(256, 2)
__global__ void k_edge_mix(const float* __restrict__ ev, const float* __restrict__ emb,
                           const u16* __restrict__ enbf, float* __restrict__ neweI) {
  __shared__ float EVL[64 * 12];  // ev slice [64 m][8 h], stride 12 (16B-aligned)
  const int t = threadIdx.x;
  const int lane = t & 63;
  const int w = t >> 6;
  const int row16 = lane & 15;
  const int kg = lane >> 4;
  const int b = blockIdx.z;
  const int mt = blockIdx.x;
  const int h0 = blockIdx.y * 8;
  const int mbase = mt * 64;

  // stage ev slice once
  if (t < 64) {
    const int ml = mbase + t;
    const float* src = ev + ((size_t)b * Ev + ml) * Hv + h0;
    const f32x4 z = {0.f, 0.f, 0.f, 0.f};
#pragma unroll
    for (int q = 0; q < 2; ++q) {
      f32x4 v = (ml < Ev) ? *(const f32x4*)(src + q * 4) : z;
      *(f32x4*)&EVL[t * 12 + q * 4] = v;
    }
  }

  // B-frags once: emb[mbase + mf*16 + row16][kk*32 + kg*8 ..+8] -> bf16 regs (64 m)
  bf16x8 bfrag[4][4];
#pragma unroll
  for (int mf = 0; mf < 4; ++mf) {
    const int ml = mbase + mf * 16 + row16;
    const float* src = emb + ((size_t)b * Ev + ml) * Hv;
#pragma unroll
    for (int kk = 0; kk < 4; ++kk) {
      f32x4 x0 = {0.f, 0.f, 0.f, 0.f}, x1 = {0.f, 0.f, 0.f, 0.f};
      if (ml < Ev) {
        const f32x4* p = (const f32x4*)(src + kk * 32 + kg * 8);
        x0 = p[0];
        x1 = p[1];
      }
      union { bf16x8 v; uint4 u; } c;
      c.u.x = pack2bf(x0.x, x0.y);
      c.u.y = pack2bf(x0.z, x0.w);
      c.u.z = pack2bf(x1.x, x1.y);
      c.u.w = pack2bf(x1.z, x1.w);
      bfrag[mf][kk] = c.v;
    }
  }
  __syncthreads();

  const f32x4 zero4 = {0.f, 0.f, 0.f, 0.f};
  f32x4 pers[2][4];
#pragma unroll
  for (int fi = 0; fi < 2; ++fi)
#pragma unroll
    for (int mf = 0; mf < 4; ++mf) pers[fi][mf] = zero4;

  const int irow0 = w * 32 + row16;  // wave's i base row (+fi*16)
  const int kcol = kg * 8;

  auto LDA = [&](int hh, bf16x8 a[2][4]) {
    const u16* __restrict__ bh = enbf + (size_t)(h0 + hh) * 16384;
#pragma unroll
    for (int fi = 0; fi < 2; ++fi)
#pragma unroll
      for (int kk = 0; kk < 4; ++kk)
        a[fi][kk] = *(const bf16x8*)(bh + (size_t)(irow0 + fi * 16) * 128 + kk * 32 + kcol);
  };
  auto STEP = [&](int hh, bf16x8 a[2][4]) {
    f32x4 q[2][4];
#pragma unroll
    for (int fi = 0; fi < 2; ++fi)
#pragma unroll
      for (int mf = 0; mf < 4; ++mf)
        q[fi][mf] = __builtin_amdgcn_mfma_f32_16x16x32_bf16(a[fi][0], bfrag[mf][0], zero4, 0, 0, 0);
#pragma unroll
    for (int kk = 1; kk < 4; ++kk)
#pragma unroll
      for (int fi = 0; fi < 2; ++fi)
#pragma unroll
        for (int mf = 0; mf < 4; ++mf)
          q[fi][mf] = __builtin_amdgcn_mfma_f32_16x16x32_bf16(a[fi][kk], bfrag[mf][kk], q[fi][mf], 0, 0, 0);
    float evv[4];
#pragma unroll
    for (int mf = 0; mf < 4; ++mf)
      evv[mf] = EVL[(mf * 16 + row16) * 12 + hh];
#pragma unroll
    for (int fi = 0; fi < 2; ++fi)
#pragma unroll
      for (int mf = 0; mf < 4; ++mf)
        pers[fi][mf] += evv[mf] * q[fi][mf];
  };

  bf16x8 aA[2][4], aB[2][4];
  LDA(0, aA);
#pragma unroll 1
  for (int hh = 0; hh < 8; hh += 2) {
    LDA(hh + 1, aB);   // issue next loads before consuming aA
    STEP(hh, aA);
    if (hh + 2 < 8) LDA(hh + 2, aA);
    STEP(hh + 1, aB);
  }

  // atomic fold into neweI[b][i][m] (i-major = agg GEMM's B^T layout)
#pragma unroll
  for (int fi = 0; fi < 2; ++fi) {
#pragma unroll
    for (int mf = 0; mf < 4; ++mf) {
      const int ml = mbase + mf * 16 + row16;
      if (ml < Ev) {
#pragma unroll
        for (int r = 0; r < 4; ++r) {
          const int irow = w * 32 + fi * 16 + kg * 4 + r;
          atomicAdd(&neweI[((size_t)b * 128 + irow) * 2048 + ml], pers[fi][mf][r]);
        }
      }
    }
  }
}

extern "C" void kernel_launch(void* const* d_in, const int* in_sizes, int n_in,
                              void* d_out, int out_size, void* d_ws, size_t ws_size,
                              hipStream_t stream) {
  const float* ns  = (const float*)d_in[0];  // node_state  [B][N][H]
  const float* ev  = (const float*)d_in[1];  // edge_vec    [B][E][H]
  const float* n2e = (const float*)d_in[2];  // node2edge   [B][E][N]
  const float* e2n = (const float*)d_in[3];  // edge2node   [B][N][E]
  const float* en  = (const float*)d_in[4];  // edge_network[H][H][H]
  float* out = (float*)d_out;

  char* ws = (char*)d_ws;
  // Contiguous zero-region [0 .. 4,153,344): embacc + normacc + neweI
  float* embacc  = (float*)(ws);              // [4000][128] f32, 2,048,000 — dead after edge_mix
  float* normacc = (float*)(ws + 2048000);    // [2][1000] f32 (+pad), 8,192
  float* neweI   = (float*)(ws + 2056192);    // [2][128][2048] f32, 2,097,152 (i-major)
  u16*   enbf    = (u16*)  (ws + 4153344);    // [128][128][128] bf16, 4,194,304 — dead after edge_mix
  u16*   nsT     = (u16*)  (ws + 8347648);    // [2][128][1024] bf16, 524,288 (own region)
  float* aggacc  = (float*)(ws + 4153344);    // [2][1000][128] f32, 1,024,000 — overlays enbf late
  u16*   neweT   = (u16*)  (ws);              // [2][128][2048] bf16, 1,048,576 — overlays embacc late

  hipMemsetAsync(ws, 0, 4153344, stream);                 // zero embacc + normacc + neweI
  k_cvt_en <<<dim3(1024),     dim3(256), 0, stream>>>(en, enbf);
  k_tr_cvt <<<dim3(32, 4, 2), dim3(256), 0, stream>>>(ns, nsT, Nv, Hv, 1024);
  k_gemm_split<2000, 1000, 1024, false><<<dim3(32, 8, 2), dim3(256), 0, stream>>>(n2e, nsT, embacc, nullptr);
  k_edge_mix<<<dim3(32, 16, 2), dim3(256), 0, stream>>>(ev, embacc, enbf, neweI);
  hipMemsetAsync(aggacc, 0, 1024000, stream);             // enbf dead now
  k_cvt<<<dim3(256), dim3(256), 0, stream>>>(neweI, neweT);  // embacc dead now
  k_gemm_split<1000, 2000, 2048, true><<<dim3(16, 16, 2), dim3(256), 0, stream>>>(e2n, neweT, aggacc, normacc);
  k_epi<<<dim3(250), dim3(256), 0, stream>>>(aggacc, ns, normacc, out);
}

// Round 9
// 117.952 us; speedup vs baseline: 1.7908x; 1.0993x over previous
//
#include <hip/hip_runtime.h>
#include <hip/hip_bf16.h>
#include <stdint.h>

#define Bv 2
#define Nv 1000
#define Ev 2000
#define Hv 128
#define Mv 4000  // Bv*Ev

typedef __attribute__((ext_vector_type(8))) short bf16x8;
typedef __attribute__((ext_vector_type(4))) float f32x4;
typedef unsigned short u16;
typedef unsigned int u32;

static __device__ __forceinline__ u32 pack2bf(float a, float b) {
  union { __hip_bfloat162 h; u32 u; } c;
  c.h = __float22bfloat162_rn(make_float2(a, b));
  return c.u;
}
static __device__ __forceinline__ u16 cvt1bf(float a) {
  return (u16)(pack2bf(a, 0.f) & 0xffffu);
}

// edge_network fp32 [H][H][H] -> bf16, same (h,i,j) layout. 2M elems, 8/thread.
__global__ void k_cvt_en(const float* __restrict__ en, u16* __restrict__ enbf) {
  size_t idx = ((size_t)blockIdx.x * 256u + threadIdx.x) * 8u;
  const f32x4* p = (const f32x4*)(en + idx);
  f32x4 a = p[0], b = p[1];
  uint4 o;
  o.x = pack2bf(a.x, a.y);
  o.y = pack2bf(a.z, a.w);
  o.z = pack2bf(b.x, b.y);
  o.w = pack2bf(b.z, b.w);
  *(uint4*)(enbf + idx) = o;
}

// Transpose+convert: src fp32 [R][C] -> dst bf16 [C][Rpad], zero-filled rows R..Rpad.
__global__ void k_tr_cvt(const float* __restrict__ src, u16* __restrict__ dst,
                         int R, int C, int Rpad) {
  __shared__ float tile[32][33];
  const int z = blockIdx.z;
  src += (size_t)z * R * C;
  dst += (size_t)z * C * Rpad;
  const int r0 = blockIdx.x * 32, c0 = blockIdx.y * 32;
  const int tx = threadIdx.x & 31, ty = threadIdx.x >> 5;
#pragma unroll
  for (int rr = 0; rr < 4; ++rr) {
    int r = r0 + ty + rr * 8;
    int c = c0 + tx;
    float v = (r < R && c < C) ? src[(size_t)r * C + c] : 0.f;
    tile[ty + rr * 8][tx] = v;
  }
  __syncthreads();
#pragma unroll
  for (int rr = 0; rr < 4; ++rr) {
    int oc = c0 + ty + rr * 8;  // dst row = src col
    int orr = r0 + tx;          // dst col = src row
    if (oc < C)
      dst[(size_t)oc * Rpad + orr] = cvt1bf(tile[tx][ty + rr * 8]);
  }
}

// Straight fp32 -> bf16 convert (no transpose). 8 elems/thread.
__global__ void k_cvt(const float* __restrict__ src, u16* __restrict__ dst) {
  size_t idx = ((size_t)blockIdx.x * 256u + threadIdx.x) * 8u;
  const f32x4* p = (const f32x4*)(src + idx);
  f32x4 a = p[0], b = p[1];
  uint4 o;
  o.x = pack2bf(a.x, a.y);
  o.y = pack2bf(a.z, a.w);
  o.z = pack2bf(b.x, b.y);
  o.w = pack2bf(b.z, b.w);
  *(uint4*)(dst + idx) = o;
}

// Split-K GEMM partial: Cacc[m,i] += sum_{k in chunk} A[m,k]*BT[i,k]
template <int M, int KREAL, int KPAD, bool ROWSUM>
__launch_bounds__(256, 4)
__global__ void k_gemm_split(const float* __restrict__ A, const u16* __restrict__ BT,
                             float* __restrict__ Cacc, float* __restrict__ nrmacc) {
  __shared__ u16 AL[64 * 136];
  __shared__ float rowsum[64];
  const int b = blockIdx.z;
  A    += (size_t)b * M * KREAL;
  BT   += (size_t)b * 128 * KPAD;
  Cacc += (size_t)b * M * 128;
  if (ROWSUM) nrmacc += (size_t)b * M;
  const int t = threadIdx.x;
  const int lane = t & 63;
  const int w = t >> 6;
  const int row16 = lane & 15;
  const int kg = lane >> 4;
  const int mrow0 = blockIdx.x * 64;
  const int kc = blockIdx.y * 128;
  const int mtg = (w >> 1) * 2;
  const int itg = (w & 1) * 4;
  f32x4 acc[2][4];
#pragma unroll
  for (int i = 0; i < 2; ++i)
#pragma unroll
    for (int j = 0; j < 4; ++j) acc[i][j] = (f32x4){0.f, 0.f, 0.f, 0.f};
  if (ROWSUM && t < 64) rowsum[t] = 0.f;
  __syncthreads();
#pragma unroll
  for (int r = 0; r < 4; ++r) {
    const int chunk = t + r * 256;
    const int m = chunk >> 4;
    const int jc = (chunk & 15) * 8;
    const int gm = mrow0 + m;
    const int gk = kc + jc;
    f32x4 x0 = {0.f, 0.f, 0.f, 0.f}, x1 = {0.f, 0.f, 0.f, 0.f};
    if (gm < M && gk + 8 <= KREAL) {
      const f32x4* p = (const f32x4*)(A + (size_t)gm * KREAL + gk);
      x0 = p[0];
      x1 = p[1];
    }
    if (ROWSUM) {
      float s8 = x0.x + x0.y + x0.z + x0.w + x1.x + x1.y + x1.z + x1.w;
      s8 += __shfl_down(s8, 8, 16);
      s8 += __shfl_down(s8, 4, 16);
      s8 += __shfl_down(s8, 2, 16);
      s8 += __shfl_down(s8, 1, 16);
      if ((lane & 15) == 0) rowsum[m] += s8;
    }
    uint4 o;
    o.x = pack2bf(x0.x, x0.y);
    o.y = pack2bf(x0.z, x0.w);
    o.z = pack2bf(x1.x, x1.y);
    o.w = pack2bf(x1.z, x1.w);
    *(uint4*)&AL[m * 136 + jc] = o;
  }
  __syncthreads();
#pragma unroll
  for (int kk = 0; kk < 4; ++kk) {
    bf16x8 a[2], bfr[4];
#pragma unroll
    for (int q = 0; q < 2; ++q)
      a[q] = *(const bf16x8*)&AL[((mtg + q) * 16 + row16) * 136 + kk * 32 + kg * 8];
#pragma unroll
    for (int q = 0; q < 4; ++q)
      bfr[q] = *(const bf16x8*)(BT + (size_t)((itg + q) * 16 + row16) * KPAD + kc + kk * 32 + kg * 8);
#pragma unroll
    for (int mi = 0; mi < 2; ++mi)
#pragma unroll
      for (int ii = 0; ii < 4; ++ii)
        acc[mi][ii] = __builtin_amdgcn_mfma_f32_16x16x32_bf16(a[mi], bfr[ii], acc[mi][ii], 0, 0, 0);
  }
  if (ROWSUM && t < 64 && mrow0 + t < M) atomicAdd(&nrmacc[mrow0 + t], rowsum[t]);
#pragma unroll
  for (int mi = 0; mi < 2; ++mi) {
#pragma unroll
    for (int r = 0; r < 4; ++r) {
      const int lrow = (mtg + mi) * 16 + kg * 4 + r;
      const int gm = mrow0 + lrow;
      if (gm < M) {
#pragma unroll
        for (int ii = 0; ii < 4; ++ii)
          atomicAdd(&Cacc[(size_t)gm * 128 + (itg + ii) * 16 + row16], acc[mi][ii][r]);
      }
    }
  }
}

// out = (aggacc + ns) / (norm + 1)
__global__ void k_epi(const float* __restrict__ acc, const float* __restrict__ ns,
                      const float* __restrict__ nrm, float* __restrict__ out) {
  const int idx = (blockIdx.x * 256 + threadIdx.x) * 4;
  f32x4 a = *(const f32x4*)(acc + idx);
  f32x4 s = *(const f32x4*)(ns + idx);
  const int row = idx >> 7;
  float inv = 1.f / (nrm[row] + 1.0f);
  *(f32x4*)(out + idx) = (a + s) * inv;
}

// v7: round-6 body (256 thr, 16 h/block, reg dbuf A) + XCD-pinned h-groups.
// blockIdx.x % 8 == XCD on MI355X round-robin dispatch, so hgrp = id&7 keeps
// each XCD's 16 EN planes (512 KB bf16) resident in ITS 4 MB L2 all dispatch.
// neweI[b][i][m] += sum_{h in grp} ev[m,h] * (EN[h] @ emb^T)[i,m]
// Flat grid 512 = (8 hgrp) x (32 mt) x (2 b), 256 thr.
__launch_bounds__(256, 2)
__global__ void k_edge_mix(const float* __restrict__ ev, const float* __restrict__ emb,
                           const u16* __restrict__ enbf, float* __restrict__ neweI) {
  __shared__ float EVL[64 * 20];  // ev slice [64 m][16 h], stride 20
  const int id = blockIdx.x;
  const int hgrp = id & 7;        // XCD affinity
  const int rest = id >> 3;       // 0..63
  const int mt = rest & 31;
  const int b = rest >> 5;
  const int h0 = hgrp * 16;
  const int t = threadIdx.x;
  const int lane = t & 63;
  const int w = t >> 6;
  const int row16 = lane & 15;
  const int kg = lane >> 4;
  const int mbase = mt * 64;

  // stage ev slice once
  if (t < 64) {
    const int ml = mbase + t;
    const float* src = ev + ((size_t)b * Ev + ml) * Hv + h0;
    const f32x4 z = {0.f, 0.f, 0.f, 0.f};
#pragma unroll
    for (int q = 0; q < 4; ++q) {
      f32x4 v = (ml < Ev) ? *(const f32x4*)(src + q * 4) : z;
      *(f32x4*)&EVL[t * 20 + q * 4] = v;
    }
  }

  // B-frags once: emb[mbase + mf*16 + row16][kk*32 + kg*8 ..+8] -> bf16 regs (64 m)
  bf16x8 bfrag[4][4];
#pragma unroll
  for (int mf = 0; mf < 4; ++mf) {
    const int ml = mbase + mf * 16 + row16;
    const float* src = emb + ((size_t)b * Ev + ml) * Hv;
#pragma unroll
    for (int kk = 0; kk < 4; ++kk) {
      f32x4 x0 = {0.f, 0.f, 0.f, 0.f}, x1 = {0.f, 0.f, 0.f, 0.f};
      if (ml < Ev) {
        const f32x4* p = (const f32x4*)(src + kk * 32 + kg * 8);
        x0 = p[0];
        x1 = p[1];
      }
      union { bf16x8 v; uint4 u; } c;
      c.u.x = pack2bf(x0.x, x0.y);
      c.u.y = pack2bf(x0.z, x0.w);
      c.u.z = pack2bf(x1.x, x1.y);
      c.u.w = pack2bf(x1.z, x1.w);
      bfrag[mf][kk] = c.v;
    }
  }
  __syncthreads();

  const f32x4 zero4 = {0.f, 0.f, 0.f, 0.f};
  f32x4 pers[2][4];
#pragma unroll
  for (int fi = 0; fi < 2; ++fi)
#pragma unroll
    for (int mf = 0; mf < 4; ++mf) pers[fi][mf] = zero4;

  const int irow0 = w * 32 + row16;  // wave's i base row (+fi*16)
  const int kcol = kg * 8;

  auto LDA = [&](int hh, bf16x8 a[2][4]) {
    const u16* __restrict__ bh = enbf + (size_t)(h0 + hh) * 16384;
#pragma unroll
    for (int fi = 0; fi < 2; ++fi)
#pragma unroll
      for (int kk = 0; kk < 4; ++kk)
        a[fi][kk] = *(const bf16x8*)(bh + (size_t)(irow0 + fi * 16) * 128 + kk * 32 + kcol);
  };
  auto STEP = [&](int hh, bf16x8 a[2][4]) {
    f32x4 q[2][4];
#pragma unroll
    for (int fi = 0; fi < 2; ++fi)
#pragma unroll
      for (int mf = 0; mf < 4; ++mf)
        q[fi][mf] = __builtin_amdgcn_mfma_f32_16x16x32_bf16(a[fi][0], bfrag[mf][0], zero4, 0, 0, 0);
#pragma unroll
    for (int kk = 1; kk < 4; ++kk)
#pragma unroll
      for (int fi = 0; fi < 2; ++fi)
#pragma unroll
        for (int mf = 0; mf < 4; ++mf)
          q[fi][mf] = __builtin_amdgcn_mfma_f32_16x16x32_bf16(a[fi][kk], bfrag[mf][kk], q[fi][mf], 0, 0, 0);
    float evv[4];
#pragma unroll
    for (int mf = 0; mf < 4; ++mf)
      evv[mf] = EVL[(mf * 16 + row16) * 20 + hh];
#pragma unroll
    for (int fi = 0; fi < 2; ++fi)
#pragma unroll
      for (int mf = 0; mf < 4; ++mf)
        pers[fi][mf] += evv[mf] * q[fi][mf];
  };

  bf16x8 aA[2][4], aB[2][4];
  LDA(0, aA);
#pragma unroll 1
  for (int hh = 0; hh < 16; hh += 2) {
    LDA(hh + 1, aB);   // issue next loads before consuming aA
    STEP(hh, aA);
    if (hh + 2 < 16) LDA(hh + 2, aA);
    STEP(hh + 1, aB);
  }

  // atomic fold into neweI[b][i][m] (i-major = agg GEMM's B^T layout)
#pragma unroll
  for (int fi = 0; fi < 2; ++fi) {
#pragma unroll
    for (int mf = 0; mf < 4; ++mf) {
      const int ml = mbase + mf * 16 + row16;
      if (ml < Ev) {
#pragma unroll
        for (int r = 0; r < 4; ++r) {
          const int irow = w * 32 + fi * 16 + kg * 4 + r;
          atomicAdd(&neweI[((size_t)b * 128 + irow) * 2048 + ml], pers[fi][mf][r]);
        }
      }
    }
  }
}

extern "C" void kernel_launch(void* const* d_in, const int* in_sizes, int n_in,
                              void* d_out, int out_size, void* d_ws, size_t ws_size,
                              hipStream_t stream) {
  const float* ns  = (const float*)d_in[0];  // node_state  [B][N][H]
  const float* ev  = (const float*)d_in[1];  // edge_vec    [B][E][H]
  const float* n2e = (const float*)d_in[2];  // node2edge   [B][E][N]
  const float* e2n = (const float*)d_in[3];  // edge2node   [B][N][E]
  const float* en  = (const float*)d_in[4];  // edge_network[H][H][H]
  float* out = (float*)d_out;

  char* ws = (char*)d_ws;
  // Contiguous zero-region [0 .. 4,153,344): embacc + normacc + neweI
  float* embacc  = (float*)(ws);              // [4000][128] f32, 2,048,000 — dead after edge_mix
  float* normacc = (float*)(ws + 2048000);    // [2][1000] f32 (+pad), 8,192
  float* neweI   = (float*)(ws + 2056192);    // [2][128][2048] f32, 2,097,152 (i-major)
  u16*   enbf    = (u16*)  (ws + 4153344);    // [128][128][128] bf16, 4,194,304 — dead after edge_mix
  u16*   nsT     = (u16*)  (ws + 8347648);    // [2][128][1024] bf16, 524,288 (own region)
  float* aggacc  = (float*)(ws + 4153344);    // [2][1000][128] f32, 1,024,000 — overlays enbf late
  u16*   neweT   = (u16*)  (ws);              // [2][128][2048] bf16, 1,048,576 — overlays embacc late

  hipMemsetAsync(ws, 0, 4153344, stream);                 // zero embacc + normacc + neweI
  k_cvt_en <<<dim3(1024),     dim3(256), 0, stream>>>(en, enbf);
  k_tr_cvt <<<dim3(32, 4, 2), dim3(256), 0, stream>>>(ns, nsT, Nv, Hv, 1024);
  k_gemm_split<2000, 1000, 1024, false><<<dim3(32, 8, 2), dim3(256), 0, stream>>>(n2e, nsT, embacc, nullptr);
  k_edge_mix<<<dim3(512), dim3(256), 0, stream>>>(ev, embacc, enbf, neweI);
  hipMemsetAsync(aggacc, 0, 1024000, stream);             // enbf dead now
  k_cvt<<<dim3(256), dim3(256), 0, stream>>>(neweI, neweT);  // embacc dead now
  k_gemm_split<1000, 2000, 2048, true><<<dim3(16, 16, 2), dim3(256), 0, stream>>>(e2n, neweT, aggacc, normacc);
  k_epi<<<dim3(250), dim3(256), 0, stream>>>(aggacc, ns, normacc, out);
}

// Round 10
// 106.981 us; speedup vs baseline: 1.9745x; 1.1025x over previous
//
#include <hip/hip_runtime.h>
#include <hip/hip_bf16.h>
#include <stdint.h>

#define Bv 2
#define Nv 1000
#define Ev 2000
#define Hv 128
#define Mv 4000  // Bv*Ev

typedef __attribute__((ext_vector_type(8))) short bf16x8;
typedef __attribute__((ext_vector_type(4))) float f32x4;
typedef unsigned short u16;
typedef unsigned int u32;

static __device__ __forceinline__ u32 pack2bf(float a, float b) {
  union { __hip_bfloat162 h; u32 u; } c;
  c.h = __float22bfloat162_rn(make_float2(a, b));
  return c.u;
}
static __device__ __forceinline__ u16 cvt1bf(float a) {
  return (u16)(pack2bf(a, 0.f) & 0xffffu);
}

// async global->LDS, 16B per lane (wave-uniform LDS base + lane*16)
static __device__ __forceinline__ void gload_lds16(const void* g, void* l) {
  __builtin_amdgcn_global_load_lds(
      (const __attribute__((address_space(1))) void*)g,
      (__attribute__((address_space(3))) void*)l, 16, 0, 0);
}

// edge_network fp32 [H][H][H] -> bf16, same (h,i,j) layout. 2M elems, 8/thread.
__global__ void k_cvt_en(const float* __restrict__ en, u16* __restrict__ enbf) {
  size_t idx = ((size_t)blockIdx.x * 256u + threadIdx.x) * 8u;
  const f32x4* p = (const f32x4*)(en + idx);
  f32x4 a = p[0], b = p[1];
  uint4 o;
  o.x = pack2bf(a.x, a.y);
  o.y = pack2bf(a.z, a.w);
  o.z = pack2bf(b.x, b.y);
  o.w = pack2bf(b.z, b.w);
  *(uint4*)(enbf + idx) = o;
}

// Transpose+convert: src fp32 [R][C] -> dst bf16 [C][Rpad], zero-filled rows R..Rpad.
__global__ void k_tr_cvt(const float* __restrict__ src, u16* __restrict__ dst,
                         int R, int C, int Rpad) {
  __shared__ float tile[32][33];
  const int z = blockIdx.z;
  src += (size_t)z * R * C;
  dst += (size_t)z * C * Rpad;
  const int r0 = blockIdx.x * 32, c0 = blockIdx.y * 32;
  const int tx = threadIdx.x & 31, ty = threadIdx.x >> 5;
#pragma unroll
  for (int rr = 0; rr < 4; ++rr) {
    int r = r0 + ty + rr * 8;
    int c = c0 + tx;
    float v = (r < R && c < C) ? src[(size_t)r * C + c] : 0.f;
    tile[ty + rr * 8][tx] = v;
  }
  __syncthreads();
#pragma unroll
  for (int rr = 0; rr < 4; ++rr) {
    int oc = c0 + ty + rr * 8;  // dst row = src col
    int orr = r0 + tx;          // dst col = src row
    if (oc < C)
      dst[(size_t)oc * Rpad + orr] = cvt1bf(tile[tx][ty + rr * 8]);
  }
}

// Straight fp32 -> bf16 convert (no transpose). 8 elems/thread.
__global__ void k_cvt(const float* __restrict__ src, u16* __restrict__ dst) {
  size_t idx = ((size_t)blockIdx.x * 256u + threadIdx.x) * 8u;
  const f32x4* p = (const f32x4*)(src + idx);
  f32x4 a = p[0], b = p[1];
  uint4 o;
  o.x = pack2bf(a.x, a.y);
  o.y = pack2bf(a.z, a.w);
  o.z = pack2bf(b.x, b.y);
  o.w = pack2bf(b.z, b.w);
  *(uint4*)(dst + idx) = o;
}

// Split-K GEMM partial: Cacc[m,i] += sum_{k in chunk} A[m,k]*BT[i,k]
template <int M, int KREAL, int KPAD, bool ROWSUM>
__launch_bounds__(256, 4)
__global__ void k_gemm_split(const float* __restrict__ A, const u16* __restrict__ BT,
                             float* __restrict__ Cacc, float* __restrict__ nrmacc) {
  __shared__ u16 AL[64 * 136];
  __shared__ float rowsum[64];
  const int b = blockIdx.z;
  A    += (size_t)b * M * KREAL;
  BT   += (size_t)b * 128 * KPAD;
  Cacc += (size_t)b * M * 128;
  if (ROWSUM) nrmacc += (size_t)b * M;
  const int t = threadIdx.x;
  const int lane = t & 63;
  const int w = t >> 6;
  const int row16 = lane & 15;
  const int kg = lane >> 4;
  const int mrow0 = blockIdx.x * 64;
  const int kc = blockIdx.y * 128;
  const int mtg = (w >> 1) * 2;
  const int itg = (w & 1) * 4;
  f32x4 acc[2][4];
#pragma unroll
  for (int i = 0; i < 2; ++i)
#pragma unroll
    for (int j = 0; j < 4; ++j) acc[i][j] = (f32x4){0.f, 0.f, 0.f, 0.f};
  if (ROWSUM && t < 64) rowsum[t] = 0.f;
  __syncthreads();
#pragma unroll
  for (int r = 0; r < 4; ++r) {
    const int chunk = t + r * 256;
    const int m = chunk >> 4;
    const int jc = (chunk & 15) * 8;
    const int gm = mrow0 + m;
    const int gk = kc + jc;
    f32x4 x0 = {0.f, 0.f, 0.f, 0.f}, x1 = {0.f, 0.f, 0.f, 0.f};
    if (gm < M && gk + 8 <= KREAL) {
      const f32x4* p = (const f32x4*)(A + (size_t)gm * KREAL + gk);
      x0 = p[0];
      x1 = p[1];
    }
    if (ROWSUM) {
      float s8 = x0.x + x0.y + x0.z + x0.w + x1.x + x1.y + x1.z + x1.w;
      s8 += __shfl_down(s8, 8, 16);
      s8 += __shfl_down(s8, 4, 16);
      s8 += __shfl_down(s8, 2, 16);
      s8 += __shfl_down(s8, 1, 16);
      if ((lane & 15) == 0) rowsum[m] += s8;
    }
    uint4 o;
    o.x = pack2bf(x0.x, x0.y);
    o.y = pack2bf(x0.z, x0.w);
    o.z = pack2bf(x1.x, x1.y);
    o.w = pack2bf(x1.z, x1.w);
    *(uint4*)&AL[m * 136 + jc] = o;
  }
  __syncthreads();
#pragma unroll
  for (int kk = 0; kk < 4; ++kk) {
    bf16x8 a[2], bfr[4];
#pragma unroll
    for (int q = 0; q < 2; ++q)
      a[q] = *(const bf16x8*)&AL[((mtg + q) * 16 + row16) * 136 + kk * 32 + kg * 8];
#pragma unroll
    for (int q = 0; q < 4; ++q)
      bfr[q] = *(const bf16x8*)(BT + (size_t)((itg + q) * 16 + row16) * KPAD + kc + kk * 32 + kg * 8);
#pragma unroll
    for (int mi = 0; mi < 2; ++mi)
#pragma unroll
      for (int ii = 0; ii < 4; ++ii)
        acc[mi][ii] = __builtin_amdgcn_mfma_f32_16x16x32_bf16(a[mi], bfr[ii], acc[mi][ii], 0, 0, 0);
  }
  if (ROWSUM && t < 64 && mrow0 + t < M) atomicAdd(&nrmacc[mrow0 + t], rowsum[t]);
#pragma unroll
  for (int mi = 0; mi < 2; ++mi) {
#pragma unroll
    for (int r = 0; r < 4; ++r) {
      const int lrow = (mtg + mi) * 16 + kg * 4 + r;
      const int gm = mrow0 + lrow;
      if (gm < M) {
#pragma unroll
        for (int ii = 0; ii < 4; ++ii)
          atomicAdd(&Cacc[(size_t)gm * 128 + (itg + ii) * 16 + row16], acc[mi][ii][r]);
      }
    }
  }
}

// out = (aggacc + ns) / (norm + 1)
__global__ void k_epi(const float* __restrict__ acc, const float* __restrict__ ns,
                      const float* __restrict__ nrm, float* __restrict__ out) {
  const int idx = (blockIdx.x * 256 + threadIdx.x) * 4;
  f32x4 a = *(const f32x4*)(acc + idx);
  f32x4 s = *(const f32x4*)(ns + idx);
  const int row = idx >> 7;
  float inv = 1.f / (nrm[row] + 1.0f);
  *(f32x4*)(out + idx) = (a + s) * inv;
}

// v8: 2-phase LDS-staged EN planes (T3-minimum). Per h: STAGE(next plane) via
// global_load_lds (issued BEFORE compute), ds_read A-frags (XOR-swizzled,
// bank-floor) + 32 MFMA/wave + ev-fold, one __syncthreads (drains vmcnt).
// A-operand no longer needs register double-buffering -> no reg starvation.
// XCD-pinned h-groups (blockIdx.x & 7). Grid 512 flat, 256 thr.
__launch_bounds__(256, 2)
__global__ void k_edge_mix(const float* __restrict__ ev, const float* __restrict__ emb,
                           const u16* __restrict__ enbf, float* __restrict__ neweI) {
  __shared__ u16 APL[2][16384];   // two EN h-planes, 32 KB each, XOR-swizzled
  __shared__ float EVL[64 * 20];  // ev slice [64 m][16 h], stride 20
  const int id = blockIdx.x;
  const int hgrp = id & 7;        // XCD affinity
  const int rest = id >> 3;
  const int mt = rest & 31;
  const int b = rest >> 5;
  const int h0 = hgrp * 16;
  const int t = threadIdx.x;
  const int lane = t & 63;
  const int w = t >> 6;
  const int row16 = lane & 15;
  const int kg = lane >> 4;
  const int mbase = mt * 64;

  // stage ev slice once
  if (t < 64) {
    const int ml = mbase + t;
    const float* src = ev + ((size_t)b * Ev + ml) * Hv + h0;
    const f32x4 z = {0.f, 0.f, 0.f, 0.f};
#pragma unroll
    for (int q = 0; q < 4; ++q) {
      f32x4 v = (ml < Ev) ? *(const f32x4*)(src + q * 4) : z;
      *(f32x4*)&EVL[t * 20 + q * 4] = v;
    }
  }

  // B-frags once: emb[mbase + mf*16 + row16][kk*32 + kg*8 ..+8] -> bf16 regs (64 m)
  bf16x8 bfrag[4][4];
#pragma unroll
  for (int mf = 0; mf < 4; ++mf) {
    const int ml = mbase + mf * 16 + row16;
    const float* src = emb + ((size_t)b * Ev + ml) * Hv;
#pragma unroll
    for (int kk = 0; kk < 4; ++kk) {
      f32x4 x0 = {0.f, 0.f, 0.f, 0.f}, x1 = {0.f, 0.f, 0.f, 0.f};
      if (ml < Ev) {
        const f32x4* p = (const f32x4*)(src + kk * 32 + kg * 8);
        x0 = p[0];
        x1 = p[1];
      }
      union { bf16x8 v; uint4 u; } c;
      c.u.x = pack2bf(x0.x, x0.y);
      c.u.y = pack2bf(x0.z, x0.w);
      c.u.z = pack2bf(x1.x, x1.y);
      c.u.w = pack2bf(x1.z, x1.w);
      bfrag[mf][kk] = c.v;
    }
  }

  // STAGE: copy EN plane h into LDS buf with involution colb ^= (row&7)<<4
  // applied on the GLOBAL source (LDS dest stays linear: slot c*16, c=q*256+t).
  auto STAGE = [&](u16* dst, int h) {
    const char* plane = (const char*)(enbf + (size_t)h * 16384);
#pragma unroll
    for (int q = 0; q < 8; ++q) {
      const int c = q * 256 + t;           // 16B-chunk id 0..2047
      const int row = c >> 4;              // 0..127
      const int inner = (c & 15) << 4;     // byte col within row
      const int srcb = row * 256 + (inner ^ ((row & 7) << 4));
      gload_lds16(plane + srcb, (char*)dst + c * 16);
    }
  };

  const f32x4 zero4 = {0.f, 0.f, 0.f, 0.f};
  f32x4 pers[2][4];
#pragma unroll
  for (int fi = 0; fi < 2; ++fi)
#pragma unroll
    for (int mf = 0; mf < 4; ++mf) pers[fi][mf] = zero4;

  const int xorv = (row16 & 7) << 4;  // read-side swizzle (row16&7 == row&7)

  STAGE(APL[0], h0);
  __syncthreads();  // drains staging vmcnt + publishes EVL/APL[0]

#pragma unroll 1
  for (int hh = 0; hh < 16; ++hh) {
    const u16* buf = APL[hh & 1];
    if (hh + 1 < 16) STAGE((u16*)APL[(hh & 1) ^ 1], h0 + hh + 1);
    // ds_read A-frags (swizzled) then 32 MFMA
    bf16x8 a[2][4];
#pragma unroll
    for (int fi = 0; fi < 2; ++fi) {
      const int row = w * 32 + fi * 16 + row16;
#pragma unroll
      for (int kk = 0; kk < 4; ++kk)
        a[fi][kk] = *(const bf16x8*)((const char*)buf + row * 256 + ((kk * 64 + kg * 16) ^ xorv));
    }
    f32x4 q[2][4];
#pragma unroll
    for (int fi = 0; fi < 2; ++fi)
#pragma unroll
      for (int mf = 0; mf < 4; ++mf)
        q[fi][mf] = __builtin_amdgcn_mfma_f32_16x16x32_bf16(a[fi][0], bfrag[mf][0], zero4, 0, 0, 0);
#pragma unroll
    for (int kk = 1; kk < 4; ++kk)
#pragma unroll
      for (int fi = 0; fi < 2; ++fi)
#pragma unroll
        for (int mf = 0; mf < 4; ++mf)
          q[fi][mf] = __builtin_amdgcn_mfma_f32_16x16x32_bf16(a[fi][kk], bfrag[mf][kk], q[fi][mf], 0, 0, 0);
    float evv[4];
#pragma unroll
    for (int mf = 0; mf < 4; ++mf)
      evv[mf] = EVL[(mf * 16 + row16) * 20 + hh];
#pragma unroll
    for (int fi = 0; fi < 2; ++fi)
#pragma unroll
      for (int mf = 0; mf < 4; ++mf)
        pers[fi][mf] += evv[mf] * q[fi][mf];
    __syncthreads();  // staging of next plane drained; all waves done with buf
  }

  // atomic fold into neweI[b][i][m] (i-major = agg GEMM's B^T layout)
#pragma unroll
  for (int fi = 0; fi < 2; ++fi) {
#pragma unroll
    for (int mf = 0; mf < 4; ++mf) {
      const int ml = mbase + mf * 16 + row16;
      if (ml < Ev) {
#pragma unroll
        for (int r = 0; r < 4; ++r) {
          const int irow = w * 32 + fi * 16 + kg * 4 + r;
          atomicAdd(&neweI[((size_t)b * 128 + irow) * 2048 + ml], pers[fi][mf][r]);
        }
      }
    }
  }
}

extern "C" void kernel_launch(void* const* d_in, const int* in_sizes, int n_in,
                              void* d_out, int out_size, void* d_ws, size_t ws_size,
                              hipStream_t stream) {
  const float* ns  = (const float*)d_in[0];  // node_state  [B][N][H]
  const float* ev  = (const float*)d_in[1];  // edge_vec    [B][E][H]
  const float* n2e = (const float*)d_in[2];  // node2edge   [B][E][N]
  const float* e2n = (const float*)d_in[3];  // edge2node   [B][N][E]
  const float* en  = (const float*)d_in[4];  // edge_network[H][H][H]
  float* out = (float*)d_out;

  char* ws = (char*)d_ws;
  // Contiguous zero-region [0 .. 4,153,344): embacc + normacc + neweI
  float* embacc  = (float*)(ws);              // [4000][128] f32, 2,048,000 — dead after edge_mix
  float* normacc = (float*)(ws + 2048000);    // [2][1000] f32 (+pad), 8,192
  float* neweI   = (float*)(ws + 2056192);    // [2][128][2048] f32, 2,097,152 (i-major)
  u16*   enbf    = (u16*)  (ws + 4153344);    // [128][128][128] bf16, 4,194,304 — dead after edge_mix
  u16*   nsT     = (u16*)  (ws + 8347648);    // [2][128][1024] bf16, 524,288 (own region)
  float* aggacc  = (float*)(ws + 4153344);    // [2][1000][128] f32, 1,024,000 — overlays enbf late
  u16*   neweT   = (u16*)  (ws);              // [2][128][2048] bf16, 1,048,576 — overlays embacc late

  hipMemsetAsync(ws, 0, 4153344, stream);                 // zero embacc + normacc + neweI
  k_cvt_en <<<dim3(1024),     dim3(256), 0, stream>>>(en, enbf);
  k_tr_cvt <<<dim3(32, 4, 2), dim3(256), 0, stream>>>(ns, nsT, Nv, Hv, 1024);
  k_gemm_split<2000, 1000, 1024, false><<<dim3(32, 8, 2), dim3(256), 0, stream>>>(n2e, nsT, embacc, nullptr);
  k_edge_mix<<<dim3(512), dim3(256), 0, stream>>>(ev, embacc, enbf, neweI);
  hipMemsetAsync(aggacc, 0, 1024000, stream);             // enbf dead now
  k_cvt<<<dim3(256), dim3(256), 0, stream>>>(neweI, neweT);  // embacc dead now
  k_gemm_split<1000, 2000, 2048, true><<<dim3(16, 16, 2), dim3(256), 0, stream>>>(e2n, neweT, aggacc, normacc);
  k_epi<<<dim3(250), dim3(256), 0, stream>>>(aggacc, ns, normacc, out);
}

// Round 11
// 99.426 us; speedup vs baseline: 2.1245x; 1.0760x over previous
//
#include <hip/hip_runtime.h>
#include <hip/hip_bf16.h>
#include <stdint.h>

#define Bv 2
#define Nv 1000
#define Ev 2000
#define Hv 128
#define Mv 4000  // Bv*Ev

typedef __attribute__((ext_vector_type(8))) short bf16x8;
typedef __attribute__((ext_vector_type(4))) float f32x4;
typedef unsigned short u16;
typedef unsigned int u32;

static __device__ __forceinline__ u32 pack2bf(float a, float b) {
  union { __hip_bfloat162 h; u32 u; } c;
  c.h = __float22bfloat162_rn(make_float2(a, b));
  return c.u;
}
static __device__ __forceinline__ u16 cvt1bf(float a) {
  return (u16)(pack2bf(a, 0.f) & 0xffffu);
}

// async global->LDS, 16B per lane (wave-uniform LDS base + lane*16)
static __device__ __forceinline__ void gload_lds16(const void* g, void* l) {
  __builtin_amdgcn_global_load_lds(
      (const __attribute__((address_space(1))) void*)g,
      (__attribute__((address_space(3))) void*)l, 16, 0, 0);
}

// ---------------------------------------------------------------------------
// k_prep: fused (a) edge_network fp32->bf16, (b) node_state transpose->nsT,
// (c) zero-fill of the accumulation region. Blocks:
//   [0,1024)    : cvt_en   (2M elems, 8/thread)
//   [1024,1280) : tr_cvt ns -> nsT [2][128][1024]
//   [1280,1600) : zero 5,242,880 B at ws+0 (embacc+normacc+neweI+aggacc+pad)
// ---------------------------------------------------------------------------
__global__ void k_prep(const float* __restrict__ en, u16* __restrict__ enbf,
                       const float* __restrict__ ns, u16* __restrict__ nsT,
                       float* __restrict__ zbase) {
  const int bid = blockIdx.x;
  const int t = threadIdx.x;
  if (bid < 1024) {  // ---- cvt_en ----
    size_t idx = ((size_t)bid * 256u + t) * 8u;
    const f32x4* p = (const f32x4*)(en + idx);
    f32x4 a = p[0], b = p[1];
    uint4 o;
    o.x = pack2bf(a.x, a.y);
    o.y = pack2bf(a.z, a.w);
    o.z = pack2bf(b.x, b.y);
    o.w = pack2bf(b.z, b.w);
    *(uint4*)(enbf + idx) = o;
  } else if (bid < 1280) {  // ---- tr_cvt ns -> nsT (R=1000, C=128, Rpad=1024) ----
    __shared__ float tile[32][33];
    const int zb = bid - 1024;
    const int x = zb & 31, y = (zb >> 5) & 3, z = zb >> 7;
    const float* src = ns + (size_t)z * Nv * Hv;
    u16* dst = nsT + (size_t)z * Hv * 1024;
    const int r0 = x * 32, c0 = y * 32;
    const int tx = t & 31, ty = t >> 5;
#pragma unroll
    for (int rr = 0; rr < 4; ++rr) {
      int r = r0 + ty + rr * 8;
      int c = c0 + tx;
      float v = (r < Nv) ? src[(size_t)r * Hv + c] : 0.f;
      tile[ty + rr * 8][tx] = v;
    }
    __syncthreads();
#pragma unroll
    for (int rr = 0; rr < 4; ++rr) {
      int oc = c0 + ty + rr * 8;
      int orr = r0 + tx;
      dst[(size_t)oc * 1024 + orr] = cvt1bf(tile[tx][ty + rr * 8]);
    }
  } else {  // ---- zero-fill 5,242,880 B = 320 blocks x 16 KB ----
    const int zb = bid - 1280;
    f32x4* p = (f32x4*)((char*)zbase + (size_t)zb * 16384);
    const f32x4 z = {0.f, 0.f, 0.f, 0.f};
#pragma unroll
    for (int j = 0; j < 4; ++j) p[j * 256 + t] = z;
  }
}

// Straight fp32 -> bf16 convert (no transpose). 8 elems/thread.
__global__ void k_cvt(const float* __restrict__ src, u16* __restrict__ dst) {
  size_t idx = ((size_t)blockIdx.x * 256u + threadIdx.x) * 8u;
  const f32x4* p = (const f32x4*)(src + idx);
  f32x4 a = p[0], b = p[1];
  uint4 o;
  o.x = pack2bf(a.x, a.y);
  o.y = pack2bf(a.z, a.w);
  o.z = pack2bf(b.x, b.y);
  o.w = pack2bf(b.z, b.w);
  *(uint4*)(dst + idx) = o;
}

// Split-K GEMM partial, flat grid with kc in LOW bits (XCD-pinned B panels):
// id = (b*NMT + mt)*NKC + kc.  Cacc[m,i] += sum_{k in chunk} A[m,k]*BT[i,k].
template <int M, int KREAL, int KPAD, int NKC, int NMT, bool ROWSUM>
__launch_bounds__(256, 4)
__global__ void k_gemm_flat(const float* __restrict__ A, const u16* __restrict__ BT,
                            float* __restrict__ Cacc, float* __restrict__ nrmacc) {
  __shared__ u16 AL[64 * 136];
  __shared__ float rowsum[64];
  const int id = blockIdx.x;
  const int kcid = id % NKC;            // low bits -> XCD affinity
  const int mt = (id / NKC) % NMT;
  const int b = id / (NKC * NMT);
  A    += (size_t)b * M * KREAL;
  BT   += (size_t)b * 128 * KPAD;
  Cacc += (size_t)b * M * 128;
  if (ROWSUM) nrmacc += (size_t)b * M;
  const int t = threadIdx.x;
  const int lane = t & 63;
  const int w = t >> 6;
  const int row16 = lane & 15;
  const int kg = lane >> 4;
  const int mrow0 = mt * 64;
  const int kc = kcid * 128;
  const int mtg = (w >> 1) * 2;
  const int itg = (w & 1) * 4;
  f32x4 acc[2][4];
#pragma unroll
  for (int i = 0; i < 2; ++i)
#pragma unroll
    for (int j = 0; j < 4; ++j) acc[i][j] = (f32x4){0.f, 0.f, 0.f, 0.f};
  if (ROWSUM && t < 64) rowsum[t] = 0.f;
  __syncthreads();
#pragma unroll
  for (int r = 0; r < 4; ++r) {
    const int chunk = t + r * 256;
    const int m = chunk >> 4;
    const int jc = (chunk & 15) * 8;
    const int gm = mrow0 + m;
    const int gk = kc + jc;
    f32x4 x0 = {0.f, 0.f, 0.f, 0.f}, x1 = {0.f, 0.f, 0.f, 0.f};
    if (gm < M && gk + 8 <= KREAL) {
      const f32x4* p = (const f32x4*)(A + (size_t)gm * KREAL + gk);
      x0 = p[0];
      x1 = p[1];
    }
    if (ROWSUM) {
      float s8 = x0.x + x0.y + x0.z + x0.w + x1.x + x1.y + x1.z + x1.w;
      s8 += __shfl_down(s8, 8, 16);
      s8 += __shfl_down(s8, 4, 16);
      s8 += __shfl_down(s8, 2, 16);
      s8 += __shfl_down(s8, 1, 16);
      if ((lane & 15) == 0) rowsum[m] += s8;
    }
    uint4 o;
    o.x = pack2bf(x0.x, x0.y);
    o.y = pack2bf(x0.z, x0.w);
    o.z = pack2bf(x1.x, x1.y);
    o.w = pack2bf(x1.z, x1.w);
    *(uint4*)&AL[m * 136 + jc] = o;
  }
  __syncthreads();
#pragma unroll
  for (int kk = 0; kk < 4; ++kk) {
    bf16x8 a[2], bfr[4];
#pragma unroll
    for (int q = 0; q < 2; ++q)
      a[q] = *(const bf16x8*)&AL[((mtg + q) * 16 + row16) * 136 + kk * 32 + kg * 8];
#pragma unroll
    for (int q = 0; q < 4; ++q)
      bfr[q] = *(const bf16x8*)(BT + (size_t)((itg + q) * 16 + row16) * KPAD + kc + kk * 32 + kg * 8);
#pragma unroll
    for (int mi = 0; mi < 2; ++mi)
#pragma unroll
      for (int ii = 0; ii < 4; ++ii)
        acc[mi][ii] = __builtin_amdgcn_mfma_f32_16x16x32_bf16(a[mi], bfr[ii], acc[mi][ii], 0, 0, 0);
  }
  if (ROWSUM && t < 64 && mrow0 + t < M) atomicAdd(&nrmacc[mrow0 + t], rowsum[t]);
#pragma unroll
  for (int mi = 0; mi < 2; ++mi) {
#pragma unroll
    for (int r = 0; r < 4; ++r) {
      const int lrow = (mtg + mi) * 16 + kg * 4 + r;
      const int gm = mrow0 + lrow;
      if (gm < M) {
#pragma unroll
        for (int ii = 0; ii < 4; ++ii)
          atomicAdd(&Cacc[(size_t)gm * 128 + (itg + ii) * 16 + row16], acc[mi][ii][r]);
      }
    }
  }
}

// out = (aggacc + ns) / (norm + 1)
__global__ void k_epi(const float* __restrict__ acc, const float* __restrict__ ns,
                      const float* __restrict__ nrm, float* __restrict__ out) {
  const int idx = (blockIdx.x * 256 + threadIdx.x) * 4;
  f32x4 a = *(const f32x4*)(acc + idx);
  f32x4 s = *(const f32x4*)(ns + idx);
  const int row = idx >> 7;
  float inv = 1.f / (nrm[row] + 1.0f);
  *(f32x4*)(out + idx) = (a + s) * inv;
}

// v8 (unchanged): 2-phase LDS-staged EN planes, XCD-pinned h-groups.
// neweI[b][i][m] += sum_{h in grp} ev[m,h] * (EN[h] @ emb^T)[i,m]
__launch_bounds__(256, 2)
__global__ void k_edge_mix(const float* __restrict__ ev, const float* __restrict__ emb,
                           const u16* __restrict__ enbf, float* __restrict__ neweI) {
  __shared__ u16 APL[2][16384];   // two EN h-planes, 32 KB each, XOR-swizzled
  __shared__ float EVL[64 * 20];  // ev slice [64 m][16 h], stride 20
  const int id = blockIdx.x;
  const int hgrp = id & 7;        // XCD affinity
  const int rest = id >> 3;
  const int mt = rest & 31;
  const int b = rest >> 5;
  const int h0 = hgrp * 16;
  const int t = threadIdx.x;
  const int lane = t & 63;
  const int w = t >> 6;
  const int row16 = lane & 15;
  const int kg = lane >> 4;
  const int mbase = mt * 64;

  if (t < 64) {
    const int ml = mbase + t;
    const float* src = ev + ((size_t)b * Ev + ml) * Hv + h0;
    const f32x4 z = {0.f, 0.f, 0.f, 0.f};
#pragma unroll
    for (int q = 0; q < 4; ++q) {
      f32x4 v = (ml < Ev) ? *(const f32x4*)(src + q * 4) : z;
      *(f32x4*)&EVL[t * 20 + q * 4] = v;
    }
  }

  bf16x8 bfrag[4][4];
#pragma unroll
  for (int mf = 0; mf < 4; ++mf) {
    const int ml = mbase + mf * 16 + row16;
    const float* src = emb + ((size_t)b * Ev + ml) * Hv;
#pragma unroll
    for (int kk = 0; kk < 4; ++kk) {
      f32x4 x0 = {0.f, 0.f, 0.f, 0.f}, x1 = {0.f, 0.f, 0.f, 0.f};
      if (ml < Ev) {
        const f32x4* p = (const f32x4*)(src + kk * 32 + kg * 8);
        x0 = p[0];
        x1 = p[1];
      }
      union { bf16x8 v; uint4 u; } c;
      c.u.x = pack2bf(x0.x, x0.y);
      c.u.y = pack2bf(x0.z, x0.w);
      c.u.z = pack2bf(x1.x, x1.y);
      c.u.w = pack2bf(x1.z, x1.w);
      bfrag[mf][kk] = c.v;
    }
  }

  auto STAGE = [&](u16* dst, int h) {
    const char* plane = (const char*)(enbf + (size_t)h * 16384);
#pragma unroll
    for (int q = 0; q < 8; ++q) {
      const int c = q * 256 + t;
      const int row = c >> 4;
      const int inner = (c & 15) << 4;
      const int srcb = row * 256 + (inner ^ ((row & 7) << 4));
      gload_lds16(plane + srcb, (char*)dst + c * 16);
    }
  };

  const f32x4 zero4 = {0.f, 0.f, 0.f, 0.f};
  f32x4 pers[2][4];
#pragma unroll
  for (int fi = 0; fi < 2; ++fi)
#pragma unroll
    for (int mf = 0; mf < 4; ++mf) pers[fi][mf] = zero4;

  const int xorv = (row16 & 7) << 4;

  STAGE(APL[0], h0);
  __syncthreads();

#pragma unroll 1
  for (int hh = 0; hh < 16; ++hh) {
    const u16* buf = APL[hh & 1];
    if (hh + 1 < 16) STAGE((u16*)APL[(hh & 1) ^ 1], h0 + hh + 1);
    bf16x8 a[2][4];
#pragma unroll
    for (int fi = 0; fi < 2; ++fi) {
      const int row = w * 32 + fi * 16 + row16;
#pragma unroll
      for (int kk = 0; kk < 4; ++kk)
        a[fi][kk] = *(const bf16x8*)((const char*)buf + row * 256 + ((kk * 64 + kg * 16) ^ xorv));
    }
    f32x4 q[2][4];
#pragma unroll
    for (int fi = 0; fi < 2; ++fi)
#pragma unroll
      for (int mf = 0; mf < 4; ++mf)
        q[fi][mf] = __builtin_amdgcn_mfma_f32_16x16x32_bf16(a[fi][0], bfrag[mf][0], zero4, 0, 0, 0);
#pragma unroll
    for (int kk = 1; kk < 4; ++kk)
#pragma unroll
      for (int fi = 0; fi < 2; ++fi)
#pragma unroll
        for (int mf = 0; mf < 4; ++mf)
          q[fi][mf] = __builtin_amdgcn_mfma_f32_16x16x32_bf16(a[fi][kk], bfrag[mf][kk], q[fi][mf], 0, 0, 0);
    float evv[4];
#pragma unroll
    for (int mf = 0; mf < 4; ++mf)
      evv[mf] = EVL[(mf * 16 + row16) * 20 + hh];
#pragma unroll
    for (int fi = 0; fi < 2; ++fi)
#pragma unroll
      for (int mf = 0; mf < 4; ++mf)
        pers[fi][mf] += evv[mf] * q[fi][mf];
    __syncthreads();
  }

#pragma unroll
  for (int fi = 0; fi < 2; ++fi) {
#pragma unroll
    for (int mf = 0; mf < 4; ++mf) {
      const int ml = mbase + mf * 16 + row16;
      if (ml < Ev) {
#pragma unroll
        for (int r = 0; r < 4; ++r) {
          const int irow = w * 32 + fi * 16 + kg * 4 + r;
          atomicAdd(&neweI[((size_t)b * 128 + irow) * 2048 + ml], pers[fi][mf][r]);
        }
      }
    }
  }
}

extern "C" void kernel_launch(void* const* d_in, const int* in_sizes, int n_in,
                              void* d_out, int out_size, void* d_ws, size_t ws_size,
                              hipStream_t stream) {
  const float* ns  = (const float*)d_in[0];  // node_state  [B][N][H]
  const float* ev  = (const float*)d_in[1];  // edge_vec    [B][E][H]
  const float* n2e = (const float*)d_in[2];  // node2edge   [B][E][N]
  const float* e2n = (const float*)d_in[3];  // edge2node   [B][N][E]
  const float* en  = (const float*)d_in[4];  // edge_network[H][H][H]
  float* out = (float*)d_out;

  char* ws = (char*)d_ws;
  // Zero region [0, 5,242,880) — zeroed by k_prep each launch:
  float* embacc  = (float*)(ws);              // [4000][128] f32, 2,048,000
  float* normacc = (float*)(ws + 2048000);    // [2][1000] f32 (+pad), 8,192
  float* neweI   = (float*)(ws + 2056192);    // [2][128][2048] f32, 2,097,152
  float* aggacc  = (float*)(ws + 4153344);    // [2][1000][128] f32, 1,024,000 (+pad to 5,242,880)
  // Non-zeroed:
  u16*   enbf    = (u16*)  (ws + 5242880);    // [128][128][128] bf16, 4,194,304
  u16*   nsT     = (u16*)  (ws + 9437184);    // [2][128][1024] bf16, 524,288
  u16*   neweT   = (u16*)  (ws);              // [2][128][2048] bf16, 1,048,576 — overlays dead embacc

  k_prep<<<dim3(1600), dim3(256), 0, stream>>>(en, enbf, ns, nsT, (float*)ws);
  // emb[b,e,:] = n2e[b,e,:] @ ns[b]   (M=2000, K=1000, split-K x8, kc XCD-pinned)
  k_gemm_flat<2000, 1000, 1024, 8, 32, false><<<dim3(512), dim3(256), 0, stream>>>(n2e, nsT, embacc, nullptr);
  k_edge_mix<<<dim3(512), dim3(256), 0, stream>>>(ev, embacc, enbf, neweI);
  k_cvt<<<dim3(256), dim3(256), 0, stream>>>(neweI, neweT);  // embacc dead now
  // aggacc[b,n,:] += e2n[b,n,:] @ newe[b]  (M=1000, K=2000, split-K x16, kc XCD-pinned)
  k_gemm_flat<1000, 2000, 2048, 16, 16, true><<<dim3(512), dim3(256), 0, stream>>>(e2n, neweT, aggacc, normacc);
  k_epi<<<dim3(250), dim3(256), 0, stream>>>(aggacc, ns, normacc, out);
}

// Round 12
// 71.006 us; speedup vs baseline: 2.9748x; 1.4002x over previous
//
#include <hip/hip_runtime.h>
#include <hip/hip_bf16.h>
#include <stdint.h>

#define Bv 2
#define Nv 1000
#define Ev 2000
#define Hv 128

typedef __attribute__((ext_vector_type(8))) short bf16x8;
typedef __attribute__((ext_vector_type(4))) float f32x4;
typedef unsigned short u16;
typedef unsigned int u32;

static __device__ __forceinline__ u32 pack2bf(float a, float b) {
  union { __hip_bfloat162 h; u32 u; } c;
  c.h = __float22bfloat162_rn(make_float2(a, b));
  return c.u;
}
static __device__ __forceinline__ u16 cvt1bf(float a) {
  return (u16)(pack2bf(a, 0.f) & 0xffffu);
}

// async global->LDS, 16B per lane (wave-uniform LDS base + lane*16)
static __device__ __forceinline__ void gload_lds16(const void* g, void* l) {
  __builtin_amdgcn_global_load_lds(
      (const __attribute__((address_space(1))) void*)g,
      (__attribute__((address_space(3))) void*)l, 16, 0, 0);
}

// ---------------------------------------------------------------------------
// k_prep: fused (a) edge_network fp32->bf16, (b) node_state transpose->nsT.
//   [0,1024)    : cvt_en (2M elems, 8/thread)
//   [1024,1280) : tr_cvt ns -> nsT [2][128][1024]
// ---------------------------------------------------------------------------
__global__ void k_prep(const float* __restrict__ en, u16* __restrict__ enbf,
                       const float* __restrict__ ns, u16* __restrict__ nsT) {
  const int bid = blockIdx.x;
  const int t = threadIdx.x;
  if (bid < 1024) {  // ---- cvt_en ----
    size_t idx = ((size_t)bid * 256u + t) * 8u;
    const f32x4* p = (const f32x4*)(en + idx);
    f32x4 a = p[0], b = p[1];
    uint4 o;
    o.x = pack2bf(a.x, a.y);
    o.y = pack2bf(a.z, a.w);
    o.z = pack2bf(b.x, b.y);
    o.w = pack2bf(b.z, b.w);
    *(uint4*)(enbf + idx) = o;
  } else {  // ---- tr_cvt ns -> nsT (R=1000, C=128, Rpad=1024) ----
    __shared__ float tile[32][33];
    const int zb = bid - 1024;
    const int x = zb & 31, y = (zb >> 5) & 3, z = zb >> 7;
    const float* src = ns + (size_t)z * Nv * Hv;
    u16* dst = nsT + (size_t)z * Hv * 1024;
    const int r0 = x * 32, c0 = y * 32;
    const int tx = t & 31, ty = t >> 5;
#pragma unroll
    for (int rr = 0; rr < 4; ++rr) {
      int r = r0 + ty + rr * 8;
      int c = c0 + tx;
      float v = (r < Nv) ? src[(size_t)r * Hv + c] : 0.f;
      tile[ty + rr * 8][tx] = v;
    }
    __syncthreads();
#pragma unroll
    for (int rr = 0; rr < 4; ++rr) {
      int oc = c0 + ty + rr * 8;
      int orr = r0 + tx;
      dst[(size_t)oc * 1024 + orr] = cvt1bf(tile[tx][ty + rr * 8]);
    }
  }
}

// Split-K GEMM, NO atomics: each kc block writes its private partial slice.
// part[kc][b][m][i], kc-stride = 2*M*128 floats. Grid (b*NMT+mt)*NKC + kc.
template <int M, int KREAL, int KPAD, int NKC, int NMT, bool ROWSUM>
__launch_bounds__(256, 4)
__global__ void k_gemm_flat(const float* __restrict__ A, const u16* __restrict__ BT,
                            float* __restrict__ Cpart, float* __restrict__ nrmpart) {
  __shared__ u16 AL[64 * 136];
  __shared__ float rowsum[64];
  const int id = blockIdx.x;
  const int kcid = id % NKC;            // low bits -> XCD affinity for B panel
  const int mt = (id / NKC) % NMT;
  const int b = id / (NKC * NMT);
  A     += (size_t)b * M * KREAL;
  BT    += (size_t)b * 128 * KPAD;
  Cpart += (size_t)kcid * (2 * M * 128) + (size_t)b * M * 128;
  if (ROWSUM) nrmpart += (size_t)kcid * (2 * M) + (size_t)b * M;
  const int t = threadIdx.x;
  const int lane = t & 63;
  const int w = t >> 6;
  const int row16 = lane & 15;
  const int kg = lane >> 4;
  const int mrow0 = mt * 64;
  const int kc = kcid * 128;
  const int mtg = (w >> 1) * 2;
  const int itg = (w & 1) * 4;
  f32x4 acc[2][4];
#pragma unroll
  for (int i = 0; i < 2; ++i)
#pragma unroll
    for (int j = 0; j < 4; ++j) acc[i][j] = (f32x4){0.f, 0.f, 0.f, 0.f};
  if (ROWSUM && t < 64) rowsum[t] = 0.f;
  __syncthreads();
#pragma unroll
  for (int r = 0; r < 4; ++r) {
    const int chunk = t + r * 256;
    const int m = chunk >> 4;
    const int jc = (chunk & 15) * 8;
    const int gm = mrow0 + m;
    const int gk = kc + jc;
    f32x4 x0 = {0.f, 0.f, 0.f, 0.f}, x1 = {0.f, 0.f, 0.f, 0.f};
    if (gm < M && gk + 8 <= KREAL) {
      const f32x4* p = (const f32x4*)(A + (size_t)gm * KREAL + gk);
      x0 = p[0];
      x1 = p[1];
    }
    if (ROWSUM) {
      float s8 = x0.x + x0.y + x0.z + x0.w + x1.x + x1.y + x1.z + x1.w;
      s8 += __shfl_down(s8, 8, 16);
      s8 += __shfl_down(s8, 4, 16);
      s8 += __shfl_down(s8, 2, 16);
      s8 += __shfl_down(s8, 1, 16);
      if ((lane & 15) == 0) rowsum[m] += s8;
    }
    uint4 o;
    o.x = pack2bf(x0.x, x0.y);
    o.y = pack2bf(x0.z, x0.w);
    o.z = pack2bf(x1.x, x1.y);
    o.w = pack2bf(x1.z, x1.w);
    *(uint4*)&AL[m * 136 + jc] = o;
  }
  __syncthreads();
#pragma unroll
  for (int kk = 0; kk < 4; ++kk) {
    bf16x8 a[2], bfr[4];
#pragma unroll
    for (int q = 0; q < 2; ++q)
      a[q] = *(const bf16x8*)&AL[((mtg + q) * 16 + row16) * 136 + kk * 32 + kg * 8];
#pragma unroll
    for (int q = 0; q < 4; ++q)
      bfr[q] = *(const bf16x8*)(BT + (size_t)((itg + q) * 16 + row16) * KPAD + kc + kk * 32 + kg * 8);
#pragma unroll
    for (int mi = 0; mi < 2; ++mi)
#pragma unroll
      for (int ii = 0; ii < 4; ++ii)
        acc[mi][ii] = __builtin_amdgcn_mfma_f32_16x16x32_bf16(a[mi], bfr[ii], acc[mi][ii], 0, 0, 0);
  }
  if (ROWSUM && t < 64 && mrow0 + t < M) nrmpart[mrow0 + t] = rowsum[t];
#pragma unroll
  for (int mi = 0; mi < 2; ++mi) {
#pragma unroll
    for (int r = 0; r < 4; ++r) {
      const int lrow = (mtg + mi) * 16 + kg * 4 + r;
      const int gm = mrow0 + lrow;
      if (gm < M) {
#pragma unroll
        for (int ii = 0; ii < 4; ++ii)
          Cpart[(size_t)gm * 128 + (itg + ii) * 16 + row16] = acc[mi][ii][r];
      }
    }
  }
}

// emb[b,m,i] = sum_{kc=0..7} part1[kc][b][m][i].  512,000 floats out.
__global__ void k_reduce_emb(const float* __restrict__ part, float* __restrict__ emb) {
  const int idx = blockIdx.x * 256 + threadIdx.x;  // f32x4 id, 128,000
  const f32x4* p = (const f32x4*)part + idx;
  f32x4 s = {0.f, 0.f, 0.f, 0.f};
#pragma unroll
  for (int kc = 0; kc < 8; ++kc) s += p[(size_t)kc * 128000];
  ((f32x4*)emb)[idx] = s;
}

// neweT[b][i][m] = bf16(sum_{hg=0..7} part2[hg][b][i][m]); zero for m>=2000.
__global__ void k_cvt_red(const float* __restrict__ part2, u16* __restrict__ neweT) {
  const int tid = blockIdx.x * 256 + threadIdx.x;  // 65,536
  const size_t f0 = (size_t)tid * 8;
  const int m0 = (int)(f0 & 2047);
  uint4 o;
  if (m0 >= Ev) {
    o = make_uint4(0, 0, 0, 0);
  } else {
    const f32x4* p = (const f32x4*)(part2 + f0);
    f32x4 s0 = {0.f, 0.f, 0.f, 0.f}, s1 = {0.f, 0.f, 0.f, 0.f};
#pragma unroll
    for (int hg = 0; hg < 8; ++hg) {
      s0 += p[(size_t)hg * 131072];
      s1 += p[(size_t)hg * 131072 + 1];
    }
    o.x = pack2bf(s0.x, s0.y);
    o.y = pack2bf(s0.z, s0.w);
    o.z = pack2bf(s1.x, s1.y);
    o.w = pack2bf(s1.z, s1.w);
  }
  *(uint4*)(neweT + f0) = o;
}

// out[b,n,i] = (sum_{kc=0..15} part3[kc][b,n,i] + ns) / (1 + sum_kc nrmp[kc][b,n])
__global__ void k_epi_red(const float* __restrict__ part3, const float* __restrict__ nrmp,
                          const float* __restrict__ ns, float* __restrict__ out) {
  const int tid = blockIdx.x * 256 + threadIdx.x;  // 64,000
  const size_t f0 = (size_t)tid * 4;
  const int row = (int)(f0 >> 7);  // b*1000+n
  const f32x4* p = (const f32x4*)(part3 + f0);
  f32x4 s = {0.f, 0.f, 0.f, 0.f};
#pragma unroll
  for (int kc = 0; kc < 16; ++kc) s += p[(size_t)kc * 64000];
  float nm = 1.0f;
#pragma unroll
  for (int kc = 0; kc < 16; ++kc) nm += nrmp[(size_t)kc * 2000 + row];
  f32x4 nsv = *(const f32x4*)(ns + f0);
  *(f32x4*)(out + f0) = (s + nsv) * (1.0f / nm);
}

// v9: v8 2-phase LDS pipeline, NO atomics: each hgroup writes its private
// partial slice part2[hg][b][i][m].  Grid 512 flat (hg in low 3 bits = XCD).
__launch_bounds__(256, 2)
__global__ void k_edge_mix(const float* __restrict__ ev, const float* __restrict__ emb,
                           const u16* __restrict__ enbf, float* __restrict__ part2) {
  __shared__ u16 APL[2][16384];   // two EN h-planes, 32 KB each, XOR-swizzled
  __shared__ float EVL[64 * 20];  // ev slice [64 m][16 h], stride 20
  const int id = blockIdx.x;
  const int hgrp = id & 7;        // XCD affinity
  const int rest = id >> 3;
  const int mt = rest & 31;
  const int b = rest >> 5;
  const int h0 = hgrp * 16;
  const int t = threadIdx.x;
  const int lane = t & 63;
  const int w = t >> 6;
  const int row16 = lane & 15;
  const int kg = lane >> 4;
  const int mbase = mt * 64;

  if (t < 64) {
    const int ml = mbase + t;
    const float* src = ev + ((size_t)b * Ev + ml) * Hv + h0;
    const f32x4 z = {0.f, 0.f, 0.f, 0.f};
#pragma unroll
    for (int q = 0; q < 4; ++q) {
      f32x4 v = (ml < Ev) ? *(const f32x4*)(src + q * 4) : z;
      *(f32x4*)&EVL[t * 20 + q * 4] = v;
    }
  }

  bf16x8 bfrag[4][4];
#pragma unroll
  for (int mf = 0; mf < 4; ++mf) {
    const int ml = mbase + mf * 16 + row16;
    const float* src = emb + ((size_t)b * Ev + ml) * Hv;
#pragma unroll
    for (int kk = 0; kk < 4; ++kk) {
      f32x4 x0 = {0.f, 0.f, 0.f, 0.f}, x1 = {0.f, 0.f, 0.f, 0.f};
      if (ml < Ev) {
        const f32x4* p = (const f32x4*)(src + kk * 32 + kg * 8);
        x0 = p[0];
        x1 = p[1];
      }
      union { bf16x8 v; uint4 u; } c;
      c.u.x = pack2bf(x0.x, x0.y);
      c.u.y = pack2bf(x0.z, x0.w);
      c.u.z = pack2bf(x1.x, x1.y);
      c.u.w = pack2bf(x1.z, x1.w);
      bfrag[mf][kk] = c.v;
    }
  }

  auto STAGE = [&](u16* dst, int h) {
    const char* plane = (const char*)(enbf + (size_t)h * 16384);
#pragma unroll
    for (int q = 0; q < 8; ++q) {
      const int c = q * 256 + t;
      const int row = c >> 4;
      const int inner = (c & 15) << 4;
      const int srcb = row * 256 + (inner ^ ((row & 7) << 4));
      gload_lds16(plane + srcb, (char*)dst + c * 16);
    }
  };

  const f32x4 zero4 = {0.f, 0.f, 0.f, 0.f};
  f32x4 pers[2][4];
#pragma unroll
  for (int fi = 0; fi < 2; ++fi)
#pragma unroll
    for (int mf = 0; mf < 4; ++mf) pers[fi][mf] = zero4;

  const int xorv = (row16 & 7) << 4;

  STAGE(APL[0], h0);
  __syncthreads();

#pragma unroll 1
  for (int hh = 0; hh < 16; ++hh) {
    const u16* buf = APL[hh & 1];
    if (hh + 1 < 16) STAGE((u16*)APL[(hh & 1) ^ 1], h0 + hh + 1);
    bf16x8 a[2][4];
#pragma unroll
    for (int fi = 0; fi < 2; ++fi) {
      const int row = w * 32 + fi * 16 + row16;
#pragma unroll
      for (int kk = 0; kk < 4; ++kk)
        a[fi][kk] = *(const bf16x8*)((const char*)buf + row * 256 + ((kk * 64 + kg * 16) ^ xorv));
    }
    f32x4 q[2][4];
#pragma unroll
    for (int fi = 0; fi < 2; ++fi)
#pragma unroll
      for (int mf = 0; mf < 4; ++mf)
        q[fi][mf] = __builtin_amdgcn_mfma_f32_16x16x32_bf16(a[fi][0], bfrag[mf][0], zero4, 0, 0, 0);
#pragma unroll
    for (int kk = 1; kk < 4; ++kk)
#pragma unroll
      for (int fi = 0; fi < 2; ++fi)
#pragma unroll
        for (int mf = 0; mf < 4; ++mf)
          q[fi][mf] = __builtin_amdgcn_mfma_f32_16x16x32_bf16(a[fi][kk], bfrag[mf][kk], q[fi][mf], 0, 0, 0);
    float evv[4];
#pragma unroll
    for (int mf = 0; mf < 4; ++mf)
      evv[mf] = EVL[(mf * 16 + row16) * 20 + hh];
#pragma unroll
    for (int fi = 0; fi < 2; ++fi)
#pragma unroll
      for (int mf = 0; mf < 4; ++mf)
        pers[fi][mf] += evv[mf] * q[fi][mf];
    __syncthreads();
  }

  // plain stores into this hgroup's private slice
  float* slice = part2 + (size_t)hgrp * (2 * 128 * 2048);
#pragma unroll
  for (int fi = 0; fi < 2; ++fi) {
#pragma unroll
    for (int mf = 0; mf < 4; ++mf) {
      const int ml = mbase + mf * 16 + row16;
      if (ml < Ev) {
#pragma unroll
        for (int r = 0; r < 4; ++r) {
          const int irow = w * 32 + fi * 16 + kg * 4 + r;
          slice[((size_t)b * 128 + irow) * 2048 + ml] = pers[fi][mf][r];
        }
      }
    }
  }
}

extern "C" void kernel_launch(void* const* d_in, const int* in_sizes, int n_in,
                              void* d_out, int out_size, void* d_ws, size_t ws_size,
                              hipStream_t stream) {
  const float* ns  = (const float*)d_in[0];  // node_state  [B][N][H]
  const float* ev  = (const float*)d_in[1];  // edge_vec    [B][E][H]
  const float* n2e = (const float*)d_in[2];  // node2edge   [B][E][N]
  const float* e2n = (const float*)d_in[3];  // edge2node   [B][N][E]
  const float* en  = (const float*)d_in[4];  // edge_network[H][H][H]
  float* out = (float*)d_out;

  char* ws = (char*)d_ws;
  float* part1 = (float*)(ws);               // [8][2][2000][128] f32, 16,384,000
  float* part2 = (float*)(ws + 16384000);    // [8][2][128][2048] f32, 16,777,216
  float* part3 = (float*)(ws + 33161216);    // [16][2][1000][128] f32, 16,384,000
  float* nrmp  = (float*)(ws + 49545216);    // [16][2][1000] f32, 128,000 (+pad)
  float* emb   = (float*)(ws + 49673216);    // [2][2000][128] f32, 2,048,000
  u16*   enbf  = (u16*)  (ws + 51721216);    // [128][128][128] bf16, 4,194,304
  u16*   nsT   = (u16*)  (ws + 55915520);    // [2][128][1024] bf16, 524,288
  u16*   neweT = (u16*)  (ws + 56439808);    // [2][128][2048] bf16, 1,048,576

  k_prep<<<dim3(1280), dim3(256), 0, stream>>>(en, enbf, ns, nsT);
  // part1[kc] = n2e @ nsT  (M=2000, K=1000, split-K x8, no atomics)
  k_gemm_flat<2000, 1000, 1024, 8, 32, false><<<dim3(512), dim3(256), 0, stream>>>(n2e, nsT, part1, nullptr);
  k_reduce_emb<<<dim3(500), dim3(256), 0, stream>>>(part1, emb);
  k_edge_mix<<<dim3(512), dim3(256), 0, stream>>>(ev, emb, enbf, part2);
  k_cvt_red<<<dim3(256), dim3(256), 0, stream>>>(part2, neweT);
  // part3[kc] = e2n @ neweT  (M=1000, K=2000, split-K x16, no atomics) + rowsum partials
  k_gemm_flat<1000, 2000, 2048, 16, 16, true><<<dim3(512), dim3(256), 0, stream>>>(e2n, neweT, part3, nrmp);
  k_epi_red<<<dim3(250), dim3(256), 0, stream>>>(part3, nrmp, ns, out);
}

// Round 13
// 67.204 us; speedup vs baseline: 3.1431x; 1.0566x over previous
//
#include <hip/hip_runtime.h>
#include <hip/hip_bf16.h>
#include <stdint.h>

#define Bv 2
#define Nv 1000
#define Ev 2000
#define Hv 128

typedef __attribute__((ext_vector_type(8))) short bf16x8;
typedef __attribute__((ext_vector_type(4))) float f32x4;
typedef unsigned short u16;
typedef unsigned int u32;

static __device__ __forceinline__ u32 pack2bf(float a, float b) {
  union { __hip_bfloat162 h; u32 u; } c;
  c.h = __float22bfloat162_rn(make_float2(a, b));
  return c.u;
}
static __device__ __forceinline__ u16 cvt1bf(float a) {
  return (u16)(pack2bf(a, 0.f) & 0xffffu);
}

// async global->LDS, 16B per lane (wave-uniform LDS base + lane*16)
static __device__ __forceinline__ void gload_lds16(const void* g, void* l) {
  __builtin_amdgcn_global_load_lds(
      (const __attribute__((address_space(1))) void*)g,
      (__attribute__((address_space(3))) void*)l, 16, 0, 0);
}

// ---------------------------------------------------------------------------
// k_prep: fused (a) edge_network fp32->bf16, (b) node_state transpose->nsT.
// ---------------------------------------------------------------------------
__global__ void k_prep(const float* __restrict__ en, u16* __restrict__ enbf,
                       const float* __restrict__ ns, u16* __restrict__ nsT) {
  const int bid = blockIdx.x;
  const int t = threadIdx.x;
  if (bid < 1024) {  // ---- cvt_en ----
    size_t idx = ((size_t)bid * 256u + t) * 8u;
    const f32x4* p = (const f32x4*)(en + idx);
    f32x4 a = p[0], b = p[1];
    uint4 o;
    o.x = pack2bf(a.x, a.y);
    o.y = pack2bf(a.z, a.w);
    o.z = pack2bf(b.x, b.y);
    o.w = pack2bf(b.z, b.w);
    *(uint4*)(enbf + idx) = o;
  } else {  // ---- tr_cvt ns -> nsT (R=1000, C=128, Rpad=1024) ----
    __shared__ float tile[32][33];
    const int zb = bid - 1024;
    const int x = zb & 31, y = (zb >> 5) & 3, z = zb >> 7;
    const float* src = ns + (size_t)z * Nv * Hv;
    u16* dst = nsT + (size_t)z * Hv * 1024;
    const int r0 = x * 32, c0 = y * 32;
    const int tx = t & 31, ty = t >> 5;
#pragma unroll
    for (int rr = 0; rr < 4; ++rr) {
      int r = r0 + ty + rr * 8;
      int c = c0 + tx;
      float v = (r < Nv) ? src[(size_t)r * Hv + c] : 0.f;
      tile[ty + rr * 8][tx] = v;
    }
    __syncthreads();
#pragma unroll
    for (int rr = 0; rr < 4; ++rr) {
      int oc = c0 + ty + rr * 8;
      int orr = r0 + tx;
      dst[(size_t)oc * 1024 + orr] = cvt1bf(tile[tx][ty + rr * 8]);
    }
  }
}

// Split-K GEMM, NO atomics: each kc block writes its private partial slice.
template <int M, int KREAL, int KPAD, int NKC, int NMT, bool ROWSUM>
__launch_bounds__(256, 4)
__global__ void k_gemm_flat(const float* __restrict__ A, const u16* __restrict__ BT,
                            float* __restrict__ Cpart, float* __restrict__ nrmpart) {
  __shared__ u16 AL[64 * 136];
  __shared__ float rowsum[64];
  const int id = blockIdx.x;
  const int kcid = id % NKC;            // low bits -> XCD affinity for B panel
  const int mt = (id / NKC) % NMT;
  const int b = id / (NKC * NMT);
  A     += (size_t)b * M * KREAL;
  BT    += (size_t)b * 128 * KPAD;
  Cpart += (size_t)kcid * (2 * M * 128) + (size_t)b * M * 128;
  if (ROWSUM) nrmpart += (size_t)kcid * (2 * M) + (size_t)b * M;
  const int t = threadIdx.x;
  const int lane = t & 63;
  const int w = t >> 6;
  const int row16 = lane & 15;
  const int kg = lane >> 4;
  const int mrow0 = mt * 64;
  const int kc = kcid * 128;
  const int mtg = (w >> 1) * 2;
  const int itg = (w & 1) * 4;
  f32x4 acc[2][4];
#pragma unroll
  for (int i = 0; i < 2; ++i)
#pragma unroll
    for (int j = 0; j < 4; ++j) acc[i][j] = (f32x4){0.f, 0.f, 0.f, 0.f};
  if (ROWSUM && t < 64) rowsum[t] = 0.f;
  __syncthreads();
#pragma unroll
  for (int r = 0; r < 4; ++r) {
    const int chunk = t + r * 256;
    const int m = chunk >> 4;
    const int jc = (chunk & 15) * 8;
    const int gm = mrow0 + m;
    const int gk = kc + jc;
    f32x4 x0 = {0.f, 0.f, 0.f, 0.f}, x1 = {0.f, 0.f, 0.f, 0.f};
    if (gm < M && gk + 8 <= KREAL) {
      const f32x4* p = (const f32x4*)(A + (size_t)gm * KREAL + gk);
      x0 = p[0];
      x1 = p[1];
    }
    if (ROWSUM) {
      float s8 = x0.x + x0.y + x0.z + x0.w + x1.x + x1.y + x1.z + x1.w;
      s8 += __shfl_down(s8, 8, 16);
      s8 += __shfl_down(s8, 4, 16);
      s8 += __shfl_down(s8, 2, 16);
      s8 += __shfl_down(s8, 1, 16);
      if ((lane & 15) == 0) rowsum[m] += s8;
    }
    uint4 o;
    o.x = pack2bf(x0.x, x0.y);
    o.y = pack2bf(x0.z, x0.w);
    o.z = pack2bf(x1.x, x1.y);
    o.w = pack2bf(x1.z, x1.w);
    *(uint4*)&AL[m * 136 + jc] = o;
  }
  __syncthreads();
#pragma unroll
  for (int kk = 0; kk < 4; ++kk) {
    bf16x8 a[2], bfr[4];
#pragma unroll
    for (int q = 0; q < 2; ++q)
      a[q] = *(const bf16x8*)&AL[((mtg + q) * 16 + row16) * 136 + kk * 32 + kg * 8];
#pragma unroll
    for (int q = 0; q < 4; ++q)
      bfr[q] = *(const bf16x8*)(BT + (size_t)((itg + q) * 16 + row16) * KPAD + kc + kk * 32 + kg * 8);
#pragma unroll
    for (int mi = 0; mi < 2; ++mi)
#pragma unroll
      for (int ii = 0; ii < 4; ++ii)
        acc[mi][ii] = __builtin_amdgcn_mfma_f32_16x16x32_bf16(a[mi], bfr[ii], acc[mi][ii], 0, 0, 0);
  }
  if (ROWSUM && t < 64 && mrow0 + t < M) nrmpart[mrow0 + t] = rowsum[t];
#pragma unroll
  for (int mi = 0; mi < 2; ++mi) {
#pragma unroll
    for (int r = 0; r < 4; ++r) {
      const int lrow = (mtg + mi) * 16 + kg * 4 + r;
      const int gm = mrow0 + lrow;
      if (gm < M) {
#pragma unroll
        for (int ii = 0; ii < 4; ++ii)
          Cpart[(size_t)gm * 128 + (itg + ii) * 16 + row16] = acc[mi][ii][r];
      }
    }
  }
}

// embbf[b][m][j] (bf16, m padded to 2048) = bf16( sum_{kc=0..7} part1[kc][b][m][j] )
__global__ void k_reduce_emb(const float* __restrict__ part, u16* __restrict__ embbf) {
  const int tid = blockIdx.x * 256 + threadIdx.x;  // 64,000
  const size_t e = (size_t)tid * 8;                // elem id in [2][2000][128]
  const int b = (int)(e / 256000);
  const int rem = (int)(e % 256000);
  const int m = rem >> 7;
  const int j = rem & 127;
  const f32x4* p = (const f32x4*)part + tid * 2;
  f32x4 s0 = {0.f, 0.f, 0.f, 0.f}, s1 = {0.f, 0.f, 0.f, 0.f};
#pragma unroll
  for (int kc = 0; kc < 8; ++kc) {
    s0 += p[(size_t)kc * 128000];
    s1 += p[(size_t)kc * 128000 + 1];
  }
  uint4 o;
  o.x = pack2bf(s0.x, s0.y);
  o.y = pack2bf(s0.z, s0.w);
  o.z = pack2bf(s1.x, s1.y);
  o.w = pack2bf(s1.z, s1.w);
  *(uint4*)(embbf + ((size_t)b * 2048 + m) * 128 + j) = o;
}

// neweT[b][i][m] = bf16(sum_{hg=0..7} part2[hg][b][i][m]); zero for m>=2000.
__global__ void k_cvt_red(const float* __restrict__ part2, u16* __restrict__ neweT) {
  const int tid = blockIdx.x * 256 + threadIdx.x;  // 65,536
  const size_t f0 = (size_t)tid * 8;
  const int m0 = (int)(f0 & 2047);
  uint4 o;
  if (m0 >= Ev) {
    o = make_uint4(0, 0, 0, 0);
  } else {
    const f32x4* p = (const f32x4*)(part2 + f0);
    f32x4 s0 = {0.f, 0.f, 0.f, 0.f}, s1 = {0.f, 0.f, 0.f, 0.f};
#pragma unroll
    for (int hg = 0; hg < 8; ++hg) {
      s0 += p[(size_t)hg * 131072];
      s1 += p[(size_t)hg * 131072 + 1];
    }
    o.x = pack2bf(s0.x, s0.y);
    o.y = pack2bf(s0.z, s0.w);
    o.z = pack2bf(s1.x, s1.y);
    o.w = pack2bf(s1.z, s1.w);
  }
  *(uint4*)(neweT + f0) = o;
}

// out[b,n,i] = (sum_{kc=0..15} part3[kc][b,n,i] + ns) / (1 + sum_kc nrmp[kc][b,n])
__global__ void k_epi_red(const float* __restrict__ part3, const float* __restrict__ nrmp,
                          const float* __restrict__ ns, float* __restrict__ out) {
  const int tid = blockIdx.x * 256 + threadIdx.x;  // 64,000
  const size_t f0 = (size_t)tid * 4;
  const int row = (int)(f0 >> 7);  // b*1000+n
  const f32x4* p = (const f32x4*)(part3 + f0);
  f32x4 s = {0.f, 0.f, 0.f, 0.f};
#pragma unroll
  for (int kc = 0; kc < 16; ++kc) s += p[(size_t)kc * 64000];
  float nm = 1.0f;
#pragma unroll
  for (int kc = 0; kc < 16; ++kc) nm += nrmp[(size_t)kc * 2000 + row];
  f32x4 nsv = *(const f32x4*)(ns + f0);
  *(f32x4*)(out + f0) = (s + nsv) * (1.0f / nm);
}

// v10: BARRIER-FREE h-loop. Each wave reads only rows [w*32,w*32+32) of the EN
// plane, so staging is wave-private: per-wave 8KB slice double-buffer via
// global_load_lds + counted s_waitcnt vmcnt(8) (never 0 mid-loop, T4) +
// sched_barrier fence (rule #18). No __syncthreads in the loop -> the 2
// waves/SIMD slip freely and hide L2 staging latency under MFMA.
// part2[hg][b][i][m] private slices (hg = XCD). Grid 512 flat, 256 thr.
__launch_bounds__(256, 2)
__global__ void k_edge_mix(const float* __restrict__ ev, const u16* __restrict__ embbf,
                           const u16* __restrict__ enbf, float* __restrict__ part2) {
  __shared__ u16 APL[2][4][4096];  // [buf][wave][8KB slice], XOR-swizzled rows
  __shared__ float EVL[64 * 20];   // ev slice [64 m][16 h], stride 20
  const int id = blockIdx.x;
  const int hgrp = id & 7;         // XCD affinity
  const int rest = id >> 3;
  const int mt = rest & 31;
  const int b = rest >> 5;
  const int h0 = hgrp * 16;
  const int t = threadIdx.x;
  const int lane = t & 63;
  const int w = t >> 6;
  const int row16 = lane & 15;
  const int kg = lane >> 4;
  const int mbase = mt * 64;

  // stage ev slice once (guarded: real ev rows only)
  if (t < 64) {
    const int ml = mbase + t;
    const float* src = ev + ((size_t)b * Ev + ml) * Hv + h0;
    const f32x4 z = {0.f, 0.f, 0.f, 0.f};
#pragma unroll
    for (int q = 0; q < 4; ++q) {
      f32x4 v = (ml < Ev) ? *(const f32x4*)(src + q * 4) : z;
      *(f32x4*)&EVL[t * 20 + q * 4] = v;
    }
  }

  // B-frags: direct bf16 loads from padded embbf [b][2048][128] (no cvt, no guard)
  bf16x8 bfrag[4][4];
  {
    const u16* ebase = embbf + ((size_t)b * 2048 + mbase) * 128;
#pragma unroll
    for (int mf = 0; mf < 4; ++mf) {
      const u16* rp = ebase + (size_t)(mf * 16 + row16) * 128;
#pragma unroll
      for (int kk = 0; kk < 4; ++kk)
        bfrag[mf][kk] = *(const bf16x8*)(rp + kk * 32 + kg * 8);
    }
  }

  // wave-private STAGE: this wave's 32 rows (8KB) of plane h into APL[p][w]
  auto STAGE = [&](int p, int h) {
    const char* plane = (const char*)(enbf + (size_t)h * 16384) + (size_t)w * 8192;
    char* dst = (char*)&APL[p][w][0];
#pragma unroll
    for (int it = 0; it < 8; ++it) {
      const int r = it * 4 + (lane >> 4);       // row in slice 0..31
      const int inner = (lane & 15) << 4;       // byte col
      const int srcb = r * 256 + (inner ^ ((r & 7) << 4));
      gload_lds16(plane + srcb, dst + it * 1024);
    }
  };

  const f32x4 zero4 = {0.f, 0.f, 0.f, 0.f};
  f32x4 pers[2][4];
#pragma unroll
  for (int fi = 0; fi < 2; ++fi)
#pragma unroll
    for (int mf = 0; mf < 4; ++mf) pers[fi][mf] = zero4;

  const int xorv = (row16 & 7) << 4;

  STAGE(0, h0);
  __syncthreads();  // EVL visibility only (one barrier total)

#pragma unroll 1
  for (int hh = 0; hh < 16; ++hh) {
    if (hh + 1 < 16) {
      STAGE((hh + 1) & 1, h0 + hh + 1);  // issue next slice (8 outstanding)
      asm volatile("s_waitcnt vmcnt(8)" ::: "memory");  // wait for CURRENT slice only
    } else {
      asm volatile("s_waitcnt vmcnt(0)" ::: "memory");
    }
    __builtin_amdgcn_sched_barrier(0);
    const char* sl = (const char*)&APL[hh & 1][w][0];
    bf16x8 a[2][4];
#pragma unroll
    for (int fi = 0; fi < 2; ++fi) {
      const int rs = fi * 16 + row16;
#pragma unroll
      for (int kk = 0; kk < 4; ++kk)
        a[fi][kk] = *(const bf16x8*)(sl + rs * 256 + ((kk * 64 + kg * 16) ^ xorv));
    }
    f32x4 q[2][4];
#pragma unroll
    for (int fi = 0; fi < 2; ++fi)
#pragma unroll
      for (int mf = 0; mf < 4; ++mf)
        q[fi][mf] = __builtin_amdgcn_mfma_f32_16x16x32_bf16(a[fi][0], bfrag[mf][0], zero4, 0, 0, 0);
#pragma unroll
    for (int kk = 1; kk < 4; ++kk)
#pragma unroll
      for (int fi = 0; fi < 2; ++fi)
#pragma unroll
        for (int mf = 0; mf < 4; ++mf)
          q[fi][mf] = __builtin_amdgcn_mfma_f32_16x16x32_bf16(a[fi][kk], bfrag[mf][kk], q[fi][mf], 0, 0, 0);
    float evv[4];
#pragma unroll
    for (int mf = 0; mf < 4; ++mf)
      evv[mf] = EVL[(mf * 16 + row16) * 20 + hh];
#pragma unroll
    for (int fi = 0; fi < 2; ++fi)
#pragma unroll
      for (int mf = 0; mf < 4; ++mf)
        pers[fi][mf] += evv[mf] * q[fi][mf];
  }

  // plain stores into this hgroup's private slice (cols >=2000 discarded later)
  float* slice = part2 + (size_t)hgrp * (2 * 128 * 2048);
#pragma unroll
  for (int fi = 0; fi < 2; ++fi) {
#pragma unroll
    for (int mf = 0; mf < 4; ++mf) {
      const int ml = mbase + mf * 16 + row16;
#pragma unroll
      for (int r = 0; r < 4; ++r) {
        const int irow = w * 32 + fi * 16 + kg * 4 + r;
        slice[((size_t)b * 128 + irow) * 2048 + ml] = pers[fi][mf][r];
      }
    }
  }
}

extern "C" void kernel_launch(void* const* d_in, const int* in_sizes, int n_in,
                              void* d_out, int out_size, void* d_ws, size_t ws_size,
                              hipStream_t stream) {
  const float* ns  = (const float*)d_in[0];  // node_state  [B][N][H]
  const float* ev  = (const float*)d_in[1];  // edge_vec    [B][E][H]
  const float* n2e = (const float*)d_in[2];  // node2edge   [B][E][N]
  const float* e2n = (const float*)d_in[3];  // edge2node   [B][N][E]
  const float* en  = (const float*)d_in[4];  // edge_network[H][H][H]
  float* out = (float*)d_out;

  char* ws = (char*)d_ws;
  float* part1 = (float*)(ws);               // [8][2][2000][128] f32, 16,384,000
  float* part2 = (float*)(ws + 16384000);    // [8][2][128][2048] f32, 16,777,216
  float* part3 = (float*)(ws + 33161216);    // [16][2][1000][128] f32, 16,384,000
  float* nrmp  = (float*)(ws + 49545216);    // [16][2][1000] f32, 128,000
  u16*   embbf = (u16*)  (ws + 49673216);    // [2][2048][128] bf16, 1,048,576 (padded)
  u16*   enbf  = (u16*)  (ws + 50721792);    // [128][128][128] bf16, 4,194,304
  u16*   nsT   = (u16*)  (ws + 54916096);    // [2][128][1024] bf16, 524,288
  u16*   neweT = (u16*)  (ws + 55440384);    // [2][128][2048] bf16, 1,048,576

  k_prep<<<dim3(1280), dim3(256), 0, stream>>>(en, enbf, ns, nsT);
  // part1[kc] = n2e @ nsT  (M=2000, K=1000, split-K x8, no atomics)
  k_gemm_flat<2000, 1000, 1024, 8, 32, false><<<dim3(512), dim3(256), 0, stream>>>(n2e, nsT, part1, nullptr);
  k_reduce_emb<<<dim3(250), dim3(256), 0, stream>>>(part1, embbf);
  k_edge_mix<<<dim3(512), dim3(256), 0, stream>>>(ev, embbf, enbf, part2);
  k_cvt_red<<<dim3(256), dim3(256), 0, stream>>>(part2, neweT);
  // part3[kc] = e2n @ neweT  (M=1000, K=2000, split-K x16, no atomics) + rowsum partials
  k_gemm_flat<1000, 2000, 2048, 16, 16, true><<<dim3(512), dim3(256), 0, stream>>>(e2n, neweT, part3, nrmp);
  k_epi_red<<<dim3(250), dim3(256), 0, stream>>>(part3, nrmp, ns, out);
}

// Round 14
// 63.767 us; speedup vs baseline: 3.3125x; 1.0539x over previous
//
#include <hip/hip_runtime.h>
#include <hip/hip_bf16.h>
#include <stdint.h>

#define Bv 2
#define Nv 1000
#define Ev 2000
#define Hv 128

typedef __attribute__((ext_vector_type(8))) short bf16x8;
typedef __attribute__((ext_vector_type(4))) float f32x4;
typedef unsigned short u16;
typedef unsigned int u32;

static __device__ __forceinline__ u32 pack2bf(float a, float b) {
  union { __hip_bfloat162 h; u32 u; } c;
  c.h = __float22bfloat162_rn(make_float2(a, b));
  return c.u;
}
static __device__ __forceinline__ u16 cvt1bf(float a) {
  return (u16)(pack2bf(a, 0.f) & 0xffffu);
}

// async global->LDS, 16B per lane (wave-uniform LDS base + lane*16)
static __device__ __forceinline__ void gload_lds16(const void* g, void* l) {
  __builtin_amdgcn_global_load_lds(
      (const __attribute__((address_space(1))) void*)g,
      (__attribute__((address_space(3))) void*)l, 16, 0, 0);
}

// ---------------------------------------------------------------------------
// k_prep: fused (a) edge_network fp32->bf16, (b) node_state transpose->nsT.
// ---------------------------------------------------------------------------
__global__ void k_prep(const float* __restrict__ en, u16* __restrict__ enbf,
                       const float* __restrict__ ns, u16* __restrict__ nsT) {
  const int bid = blockIdx.x;
  const int t = threadIdx.x;
  if (bid < 1024) {  // ---- cvt_en ----
    size_t idx = ((size_t)bid * 256u + t) * 8u;
    const f32x4* p = (const f32x4*)(en + idx);
    f32x4 a = p[0], b = p[1];
    uint4 o;
    o.x = pack2bf(a.x, a.y);
    o.y = pack2bf(a.z, a.w);
    o.z = pack2bf(b.x, b.y);
    o.w = pack2bf(b.z, b.w);
    *(uint4*)(enbf + idx) = o;
  } else {  // ---- tr_cvt ns -> nsT (R=1000, C=128, Rpad=1024) ----
    __shared__ float tile[32][33];
    const int zb = bid - 1024;
    const int x = zb & 31, y = (zb >> 5) & 3, z = zb >> 7;
    const float* src = ns + (size_t)z * Nv * Hv;
    u16* dst = nsT + (size_t)z * Hv * 1024;
    const int r0 = x * 32, c0 = y * 32;
    const int tx = t & 31, ty = t >> 5;
#pragma unroll
    for (int rr = 0; rr < 4; ++rr) {
      int r = r0 + ty + rr * 8;
      int c = c0 + tx;
      float v = (r < Nv) ? src[(size_t)r * Hv + c] : 0.f;
      tile[ty + rr * 8][tx] = v;
    }
    __syncthreads();
#pragma unroll
    for (int rr = 0; rr < 4; ++rr) {
      int oc = c0 + ty + rr * 8;
      int orr = r0 + tx;
      dst[(size_t)oc * 1024 + orr] = cvt1bf(tile[tx][ty + rr * 8]);
    }
  }
}

// Split-K GEMM, NO atomics. Each block handles KSTEPS consecutive 128-chunks
// and writes its private partial slice part[kcid][b][m][i].
template <int M, int KREAL, int KPAD, int NKC, int KSTEPS, int NMT, bool ROWSUM>
__launch_bounds__(256, 4)
__global__ void k_gemm_flat(const float* __restrict__ A, const u16* __restrict__ BT,
                            float* __restrict__ Cpart, float* __restrict__ nrmpart) {
  __shared__ u16 AL[64 * 136];
  __shared__ float rowsum[64];
  const int id = blockIdx.x;
  const int kcid = id % NKC;            // low bits -> XCD affinity for B panel
  const int mt = (id / NKC) % NMT;
  const int b = id / (NKC * NMT);
  A     += (size_t)b * M * KREAL;
  BT    += (size_t)b * 128 * KPAD;
  Cpart += (size_t)kcid * (2 * M * 128) + (size_t)b * M * 128;
  if (ROWSUM) nrmpart += (size_t)kcid * (2 * M) + (size_t)b * M;
  const int t = threadIdx.x;
  const int lane = t & 63;
  const int w = t >> 6;
  const int row16 = lane & 15;
  const int kg = lane >> 4;
  const int mrow0 = mt * 64;
  const int mtg = (w >> 1) * 2;
  const int itg = (w & 1) * 4;
  f32x4 acc[2][4];
#pragma unroll
  for (int i = 0; i < 2; ++i)
#pragma unroll
    for (int j = 0; j < 4; ++j) acc[i][j] = (f32x4){0.f, 0.f, 0.f, 0.f};
  if (ROWSUM && t < 64) rowsum[t] = 0.f;

#pragma unroll 1
  for (int s = 0; s < KSTEPS; ++s) {
    const int kc = (kcid * KSTEPS + s) * 128;
    __syncthreads();
#pragma unroll
    for (int r = 0; r < 4; ++r) {
      const int chunk = t + r * 256;
      const int m = chunk >> 4;
      const int jc = (chunk & 15) * 8;
      const int gm = mrow0 + m;
      const int gk = kc + jc;
      f32x4 x0 = {0.f, 0.f, 0.f, 0.f}, x1 = {0.f, 0.f, 0.f, 0.f};
      if (gm < M && gk + 8 <= KREAL) {
        const f32x4* p = (const f32x4*)(A + (size_t)gm * KREAL + gk);
        x0 = p[0];
        x1 = p[1];
      }
      if (ROWSUM) {
        float s8 = x0.x + x0.y + x0.z + x0.w + x1.x + x1.y + x1.z + x1.w;
        s8 += __shfl_down(s8, 8, 16);
        s8 += __shfl_down(s8, 4, 16);
        s8 += __shfl_down(s8, 2, 16);
        s8 += __shfl_down(s8, 1, 16);
        if ((lane & 15) == 0) rowsum[m] += s8;
      }
      uint4 o;
      o.x = pack2bf(x0.x, x0.y);
      o.y = pack2bf(x0.z, x0.w);
      o.z = pack2bf(x1.x, x1.y);
      o.w = pack2bf(x1.z, x1.w);
      *(uint4*)&AL[m * 136 + jc] = o;
    }
    __syncthreads();
#pragma unroll
    for (int kk = 0; kk < 4; ++kk) {
      bf16x8 a[2], bfr[4];
#pragma unroll
      for (int q = 0; q < 2; ++q)
        a[q] = *(const bf16x8*)&AL[((mtg + q) * 16 + row16) * 136 + kk * 32 + kg * 8];
#pragma unroll
      for (int q = 0; q < 4; ++q)
        bfr[q] = *(const bf16x8*)(BT + (size_t)((itg + q) * 16 + row16) * KPAD + kc + kk * 32 + kg * 8);
#pragma unroll
      for (int mi = 0; mi < 2; ++mi)
#pragma unroll
        for (int ii = 0; ii < 4; ++ii)
          acc[mi][ii] = __builtin_amdgcn_mfma_f32_16x16x32_bf16(a[mi], bfr[ii], acc[mi][ii], 0, 0, 0);
    }
  }
  if (ROWSUM && t < 64 && mrow0 + t < M) nrmpart[mrow0 + t] = rowsum[t];
#pragma unroll
  for (int mi = 0; mi < 2; ++mi) {
#pragma unroll
    for (int r = 0; r < 4; ++r) {
      const int lrow = (mtg + mi) * 16 + kg * 4 + r;
      const int gm = mrow0 + lrow;
      if (gm < M) {
#pragma unroll
        for (int ii = 0; ii < 4; ++ii)
          Cpart[(size_t)gm * 128 + (itg + ii) * 16 + row16] = acc[mi][ii][r];
      }
    }
  }
}

// embbf[b][m][j] (bf16, m padded to 2048) = bf16( sum_{kc=0..3} part1[kc][b][m][j] )
__global__ void k_reduce_emb(const float* __restrict__ part, u16* __restrict__ embbf) {
  const int tid = blockIdx.x * 256 + threadIdx.x;  // 64,000
  const size_t e = (size_t)tid * 8;                // elem id in [2][2000][128]
  const int b = (int)(e / 256000);
  const int rem = (int)(e % 256000);
  const int m = rem >> 7;
  const int j = rem & 127;
  const f32x4* p = (const f32x4*)part + tid * 2;
  f32x4 s0 = {0.f, 0.f, 0.f, 0.f}, s1 = {0.f, 0.f, 0.f, 0.f};
#pragma unroll
  for (int kc = 0; kc < 4; ++kc) {
    s0 += p[(size_t)kc * 128000];
    s1 += p[(size_t)kc * 128000 + 1];
  }
  uint4 o;
  o.x = pack2bf(s0.x, s0.y);
  o.y = pack2bf(s0.z, s0.w);
  o.z = pack2bf(s1.x, s1.y);
  o.w = pack2bf(s1.z, s1.w);
  *(uint4*)(embbf + ((size_t)b * 2048 + m) * 128 + j) = o;
}

// neweT[b][i][m] = bf16(sum_{hg=0..7} part2bf[hg][b][i][m]); zero for m>=2000.
__global__ void k_cvt_red(const u16* __restrict__ part2, u16* __restrict__ neweT) {
  const int tid = blockIdx.x * 256 + threadIdx.x;  // 65,536
  const size_t f0 = (size_t)tid * 8;
  const int m0 = (int)(f0 & 2047);
  uint4 o;
  if (m0 >= Ev) {
    o = make_uint4(0, 0, 0, 0);
  } else {
    float s[8] = {0.f, 0.f, 0.f, 0.f, 0.f, 0.f, 0.f, 0.f};
#pragma unroll
    for (int hg = 0; hg < 8; ++hg) {
      uint4 v = *(const uint4*)(part2 + (size_t)hg * 524288 + f0);
      u32 wv[4] = {v.x, v.y, v.z, v.w};
#pragma unroll
      for (int q = 0; q < 4; ++q) {
        s[2 * q]     += __uint_as_float(wv[q] << 16);
        s[2 * q + 1] += __uint_as_float(wv[q] & 0xffff0000u);
      }
    }
    o.x = pack2bf(s[0], s[1]);
    o.y = pack2bf(s[2], s[3]);
    o.z = pack2bf(s[4], s[5]);
    o.w = pack2bf(s[6], s[7]);
  }
  *(uint4*)(neweT + f0) = o;
}

// out[b,n,i] = (sum_{kc=0..7} part3[kc][b,n,i] + ns) / (1 + sum_kc nrmp[kc][b,n])
__global__ void k_epi_red(const float* __restrict__ part3, const float* __restrict__ nrmp,
                          const float* __restrict__ ns, float* __restrict__ out) {
  const int tid = blockIdx.x * 256 + threadIdx.x;  // 64,000
  const size_t f0 = (size_t)tid * 4;
  const int row = (int)(f0 >> 7);  // b*1000+n
  const f32x4* p = (const f32x4*)(part3 + f0);
  f32x4 s = {0.f, 0.f, 0.f, 0.f};
#pragma unroll
  for (int kc = 0; kc < 8; ++kc) s += p[(size_t)kc * 64000];
  float nm = 1.0f;
#pragma unroll
  for (int kc = 0; kc < 8; ++kc) nm += nrmp[(size_t)kc * 2000 + row];
  f32x4 nsv = *(const f32x4*)(ns + f0);
  *(f32x4*)(out + f0) = (s + nsv) * (1.0f / nm);
}

// v11: v10 barrier-free wave-private pipeline; partials stored as BF16
// (halves part2 round-trip). part2bf[hg][b][i][m]. Grid 512 flat, 256 thr.
__launch_bounds__(256, 2)
__global__ void k_edge_mix(const float* __restrict__ ev, const u16* __restrict__ embbf,
                           const u16* __restrict__ enbf, u16* __restrict__ part2) {
  __shared__ u16 APL[2][4][4096];  // [buf][wave][8KB slice], XOR-swizzled rows
  __shared__ float EVL[64 * 20];   // ev slice [64 m][16 h], stride 20
  const int id = blockIdx.x;
  const int hgrp = id & 7;         // XCD affinity
  const int rest = id >> 3;
  const int mt = rest & 31;
  const int b = rest >> 5;
  const int h0 = hgrp * 16;
  const int t = threadIdx.x;
  const int lane = t & 63;
  const int w = t >> 6;
  const int row16 = lane & 15;
  const int kg = lane >> 4;
  const int mbase = mt * 64;

  // stage ev slice once (guarded: pad rows -> 0, which zeroes their pers)
  if (t < 64) {
    const int ml = mbase + t;
    const float* src = ev + ((size_t)b * Ev + ml) * Hv + h0;
    const f32x4 z = {0.f, 0.f, 0.f, 0.f};
#pragma unroll
    for (int q = 0; q < 4; ++q) {
      f32x4 v = (ml < Ev) ? *(const f32x4*)(src + q * 4) : z;
      *(f32x4*)&EVL[t * 20 + q * 4] = v;
    }
  }

  // B-frags: direct bf16 loads from padded embbf [b][2048][128]
  bf16x8 bfrag[4][4];
  {
    const u16* ebase = embbf + ((size_t)b * 2048 + mbase) * 128;
#pragma unroll
    for (int mf = 0; mf < 4; ++mf) {
      const u16* rp = ebase + (size_t)(mf * 16 + row16) * 128;
#pragma unroll
      for (int kk = 0; kk < 4; ++kk)
        bfrag[mf][kk] = *(const bf16x8*)(rp + kk * 32 + kg * 8);
    }
  }

  // wave-private STAGE: this wave's 32 rows (8KB) of plane h into APL[p][w]
  auto STAGE = [&](int p, int h) {
    const char* plane = (const char*)(enbf + (size_t)h * 16384) + (size_t)w * 8192;
    char* dst = (char*)&APL[p][w][0];
#pragma unroll
    for (int it = 0; it < 8; ++it) {
      const int r = it * 4 + (lane >> 4);       // row in slice 0..31
      const int inner = (lane & 15) << 4;       // byte col
      const int srcb = r * 256 + (inner ^ ((r & 7) << 4));
      gload_lds16(plane + srcb, dst + it * 1024);
    }
  };

  const f32x4 zero4 = {0.f, 0.f, 0.f, 0.f};
  f32x4 pers[2][4];
#pragma unroll
  for (int fi = 0; fi < 2; ++fi)
#pragma unroll
    for (int mf = 0; mf < 4; ++mf) pers[fi][mf] = zero4;

  const int xorv = (row16 & 7) << 4;

  STAGE(0, h0);
  __syncthreads();  // EVL visibility only (one barrier total)

#pragma unroll 1
  for (int hh = 0; hh < 16; ++hh) {
    if (hh + 1 < 16) {
      STAGE((hh + 1) & 1, h0 + hh + 1);  // issue next slice (8 outstanding)
      asm volatile("s_waitcnt vmcnt(8)" ::: "memory");  // wait CURRENT slice only
    } else {
      asm volatile("s_waitcnt vmcnt(0)" ::: "memory");
    }
    __builtin_amdgcn_sched_barrier(0);
    const char* sl = (const char*)&APL[hh & 1][w][0];
    bf16x8 a[2][4];
#pragma unroll
    for (int fi = 0; fi < 2; ++fi) {
      const int rs = fi * 16 + row16;
#pragma unroll
      for (int kk = 0; kk < 4; ++kk)
        a[fi][kk] = *(const bf16x8*)(sl + rs * 256 + ((kk * 64 + kg * 16) ^ xorv));
    }
    f32x4 q[2][4];
#pragma unroll
    for (int fi = 0; fi < 2; ++fi)
#pragma unroll
      for (int mf = 0; mf < 4; ++mf)
        q[fi][mf] = __builtin_amdgcn_mfma_f32_16x16x32_bf16(a[fi][0], bfrag[mf][0], zero4, 0, 0, 0);
#pragma unroll
    for (int kk = 1; kk < 4; ++kk)
#pragma unroll
      for (int fi = 0; fi < 2; ++fi)
#pragma unroll
        for (int mf = 0; mf < 4; ++mf)
          q[fi][mf] = __builtin_amdgcn_mfma_f32_16x16x32_bf16(a[fi][kk], bfrag[mf][kk], q[fi][mf], 0, 0, 0);
    float evv[4];
#pragma unroll
    for (int mf = 0; mf < 4; ++mf)
      evv[mf] = EVL[(mf * 16 + row16) * 20 + hh];
#pragma unroll
    for (int fi = 0; fi < 2; ++fi)
#pragma unroll
      for (int mf = 0; mf < 4; ++mf)
        pers[fi][mf] += evv[mf] * q[fi][mf];
  }

  // bf16 stores into this hgroup's private slice (cols >=2000 are zero via ev guard)
  u16* slice = part2 + (size_t)hgrp * (2 * 128 * 2048);
#pragma unroll
  for (int fi = 0; fi < 2; ++fi) {
#pragma unroll
    for (int mf = 0; mf < 4; ++mf) {
      const int ml = mbase + mf * 16 + row16;
#pragma unroll
      for (int r = 0; r < 4; ++r) {
        const int irow = w * 32 + fi * 16 + kg * 4 + r;
        slice[((size_t)b * 128 + irow) * 2048 + ml] = cvt1bf(pers[fi][mf][r]);
      }
    }
  }
}

extern "C" void kernel_launch(void* const* d_in, const int* in_sizes, int n_in,
                              void* d_out, int out_size, void* d_ws, size_t ws_size,
                              hipStream_t stream) {
  const float* ns  = (const float*)d_in[0];  // node_state  [B][N][H]
  const float* ev  = (const float*)d_in[1];  // edge_vec    [B][E][H]
  const float* n2e = (const float*)d_in[2];  // node2edge   [B][E][N]
  const float* e2n = (const float*)d_in[3];  // edge2node   [B][N][E]
  const float* en  = (const float*)d_in[4];  // edge_network[H][H][H]
  float* out = (float*)d_out;

  char* ws = (char*)d_ws;
  float* part1 = (float*)(ws);               // [4][2][2000][128] f32, 8,192,000
  u16*   part2 = (u16*)  (ws + 8192000);     // [8][2][128][2048] bf16, 8,388,608
  float* part3 = (float*)(ws + 16580608);    // [8][2][1000][128] f32, 8,192,000
  float* nrmp  = (float*)(ws + 24772608);    // [8][2][1000] f32, 64,000 (+pad)
  u16*   embbf = (u16*)  (ws + 24838144);    // [2][2048][128] bf16, 1,048,576 (padded)
  u16*   enbf  = (u16*)  (ws + 25886720);    // [128][128][128] bf16, 4,194,304
  u16*   nsT   = (u16*)  (ws + 30081024);    // [2][128][1024] bf16, 524,288
  u16*   neweT = (u16*)  (ws + 30605312);    // [2][128][2048] bf16, 1,048,576

  k_prep<<<dim3(1280), dim3(256), 0, stream>>>(en, enbf, ns, nsT);
  // part1[kc] = n2e @ nsT  (M=2000, K=1000, split-K x4, 2 chunks/block)
  k_gemm_flat<2000, 1000, 1024, 4, 2, 32, false><<<dim3(256), dim3(256), 0, stream>>>(n2e, nsT, part1, nullptr);
  k_reduce_emb<<<dim3(250), dim3(256), 0, stream>>>(part1, embbf);
  k_edge_mix<<<dim3(512), dim3(256), 0, stream>>>(ev, embbf, enbf, part2);
  k_cvt_red<<<dim3(256), dim3(256), 0, stream>>>(part2, neweT);
  // part3[kc] = e2n @ neweT  (M=1000, K=2000, split-K x8, 2 chunks/block) + rowsum partials
  k_gemm_flat<1000, 2000, 2048, 8, 2, 16, true><<<dim3(256), dim3(256), 0, stream>>>(e2n, neweT, part3, nrmp);
  k_epi_red<<<dim3(250), dim3(256), 0, stream>>>(part3, nrmp, ns, out);
}

// Round 15
// 62.229 us; speedup vs baseline: 3.3944x; 1.0247x over previous
//
#include <hip/hip_runtime.h>
#include <hip/hip_bf16.h>
#include <stdint.h>

#define Bv 2
#define Nv 1000
#define Ev 2000
#define Hv 128

typedef __attribute__((ext_vector_type(8))) short bf16x8;
typedef __attribute__((ext_vector_type(4))) float f32x4;
typedef unsigned short u16;
typedef unsigned int u32;

static __device__ __forceinline__ u32 pack2bf(float a, float b) {
  union { __hip_bfloat162 h; u32 u; } c;
  c.h = __float22bfloat162_rn(make_float2(a, b));
  return c.u;
}
static __device__ __forceinline__ u16 cvt1bf(float a) {
  return (u16)(pack2bf(a, 0.f) & 0xffffu);
}

// async global->LDS, 16B per lane (wave-uniform LDS base + lane*16)
static __device__ __forceinline__ void gload_lds16(const void* g, void* l) {
  __builtin_amdgcn_global_load_lds(
      (const __attribute__((address_space(1))) void*)g,
      (__attribute__((address_space(3))) void*)l, 16, 0, 0);
}

// ---------------------------------------------------------------------------
// k_prep: fused (a) edge_network fp32->bf16, (b) node_state transpose->nsT.
// ---------------------------------------------------------------------------
__global__ void k_prep(const float* __restrict__ en, u16* __restrict__ enbf,
                       const float* __restrict__ ns, u16* __restrict__ nsT) {
  const int bid = blockIdx.x;
  const int t = threadIdx.x;
  if (bid < 1024) {  // ---- cvt_en ----
    size_t idx = ((size_t)bid * 256u + t) * 8u;
    const f32x4* p = (const f32x4*)(en + idx);
    f32x4 a = p[0], b = p[1];
    uint4 o;
    o.x = pack2bf(a.x, a.y);
    o.y = pack2bf(a.z, a.w);
    o.z = pack2bf(b.x, b.y);
    o.w = pack2bf(b.z, b.w);
    *(uint4*)(enbf + idx) = o;
  } else {  // ---- tr_cvt ns -> nsT (R=1000, C=128, Rpad=1024) ----
    __shared__ float tile[32][33];
    const int zb = bid - 1024;
    const int x = zb & 31, y = (zb >> 5) & 3, z = zb >> 7;
    const float* src = ns + (size_t)z * Nv * Hv;
    u16* dst = nsT + (size_t)z * Hv * 1024;
    const int r0 = x * 32, c0 = y * 32;
    const int tx = t & 31, ty = t >> 5;
#pragma unroll
    for (int rr = 0; rr < 4; ++rr) {
      int r = r0 + ty + rr * 8;
      int c = c0 + tx;
      float v = (r < Nv) ? src[(size_t)r * Hv + c] : 0.f;
      tile[ty + rr * 8][tx] = v;
    }
    __syncthreads();
#pragma unroll
    for (int rr = 0; rr < 4; ++rr) {
      int oc = c0 + ty + rr * 8;
      int orr = r0 + tx;
      dst[(size_t)oc * 1024 + orr] = cvt1bf(tile[tx][ty + rr * 8]);
    }
  }
}

// Split-K GEMM, NO atomics. Each block handles KSTEPS consecutive 128-chunks
// and writes its private partial slice part[kcid][b][m][i].
template <int M, int KREAL, int KPAD, int NKC, int KSTEPS, int NMT, bool ROWSUM>
__launch_bounds__(256, 4)
__global__ void k_gemm_flat(const float* __restrict__ A, const u16* __restrict__ BT,
                            float* __restrict__ Cpart, float* __restrict__ nrmpart) {
  __shared__ u16 AL[64 * 136];
  __shared__ float rowsum[64];
  const int id = blockIdx.x;
  const int kcid = id % NKC;            // low bits -> XCD affinity for B panel
  const int mt = (id / NKC) % NMT;
  const int b = id / (NKC * NMT);
  A     += (size_t)b * M * KREAL;
  BT    += (size_t)b * 128 * KPAD;
  Cpart += (size_t)kcid * (2 * M * 128) + (size_t)b * M * 128;
  if (ROWSUM) nrmpart += (size_t)kcid * (2 * M) + (size_t)b * M;
  const int t = threadIdx.x;
  const int lane = t & 63;
  const int w = t >> 6;
  const int row16 = lane & 15;
  const int kg = lane >> 4;
  const int mrow0 = mt * 64;
  const int mtg = (w >> 1) * 2;
  const int itg = (w & 1) * 4;
  f32x4 acc[2][4];
#pragma unroll
  for (int i = 0; i < 2; ++i)
#pragma unroll
    for (int j = 0; j < 4; ++j) acc[i][j] = (f32x4){0.f, 0.f, 0.f, 0.f};
  if (ROWSUM && t < 64) rowsum[t] = 0.f;

#pragma unroll 1
  for (int s = 0; s < KSTEPS; ++s) {
    const int kc = (kcid * KSTEPS + s) * 128;
    __syncthreads();
#pragma unroll
    for (int r = 0; r < 4; ++r) {
      const int chunk = t + r * 256;
      const int m = chunk >> 4;
      const int jc = (chunk & 15) * 8;
      const int gm = mrow0 + m;
      const int gk = kc + jc;
      f32x4 x0 = {0.f, 0.f, 0.f, 0.f}, x1 = {0.f, 0.f, 0.f, 0.f};
      if (gm < M && gk + 8 <= KREAL) {
        const f32x4* p = (const f32x4*)(A + (size_t)gm * KREAL + gk);
        x0 = p[0];
        x1 = p[1];
      }
      if (ROWSUM) {
        float s8 = x0.x + x0.y + x0.z + x0.w + x1.x + x1.y + x1.z + x1.w;
        s8 += __shfl_down(s8, 8, 16);
        s8 += __shfl_down(s8, 4, 16);
        s8 += __shfl_down(s8, 2, 16);
        s8 += __shfl_down(s8, 1, 16);
        if ((lane & 15) == 0) rowsum[m] += s8;
      }
      uint4 o;
      o.x = pack2bf(x0.x, x0.y);
      o.y = pack2bf(x0.z, x0.w);
      o.z = pack2bf(x1.x, x1.y);
      o.w = pack2bf(x1.z, x1.w);
      *(uint4*)&AL[m * 136 + jc] = o;
    }
    __syncthreads();
#pragma unroll
    for (int kk = 0; kk < 4; ++kk) {
      bf16x8 a[2], bfr[4];
#pragma unroll
      for (int q = 0; q < 2; ++q)
        a[q] = *(const bf16x8*)&AL[((mtg + q) * 16 + row16) * 136 + kk * 32 + kg * 8];
#pragma unroll
      for (int q = 0; q < 4; ++q)
        bfr[q] = *(const bf16x8*)(BT + (size_t)((itg + q) * 16 + row16) * KPAD + kc + kk * 32 + kg * 8);
#pragma unroll
      for (int mi = 0; mi < 2; ++mi)
#pragma unroll
        for (int ii = 0; ii < 4; ++ii)
          acc[mi][ii] = __builtin_amdgcn_mfma_f32_16x16x32_bf16(a[mi], bfr[ii], acc[mi][ii], 0, 0, 0);
    }
  }
  if (ROWSUM && t < 64 && mrow0 + t < M) nrmpart[mrow0 + t] = rowsum[t];
#pragma unroll
  for (int mi = 0; mi < 2; ++mi) {
#pragma unroll
    for (int r = 0; r < 4; ++r) {
      const int lrow = (mtg + mi) * 16 + kg * 4 + r;
      const int gm = mrow0 + lrow;
      if (gm < M) {
#pragma unroll
        for (int ii = 0; ii < 4; ++ii)
          Cpart[(size_t)gm * 128 + (itg + ii) * 16 + row16] = acc[mi][ii][r];
      }
    }
  }
}

// embbf[b][m][j] (bf16, m padded to 2048) = bf16( sum_{kc=0..3} part1[kc][b][m][j] )
__global__ void k_reduce_emb(const float* __restrict__ part, u16* __restrict__ embbf) {
  const int tid = blockIdx.x * 256 + threadIdx.x;  // 64,000
  const size_t e = (size_t)tid * 8;                // elem id in [2][2000][128]
  const int b = (int)(e / 256000);
  const int rem = (int)(e % 256000);
  const int m = rem >> 7;
  const int j = rem & 127;
  const f32x4* p = (const f32x4*)part + tid * 2;
  f32x4 s0 = {0.f, 0.f, 0.f, 0.f}, s1 = {0.f, 0.f, 0.f, 0.f};
#pragma unroll
  for (int kc = 0; kc < 4; ++kc) {
    s0 += p[(size_t)kc * 128000];
    s1 += p[(size_t)kc * 128000 + 1];
  }
  uint4 o;
  o.x = pack2bf(s0.x, s0.y);
  o.y = pack2bf(s0.z, s0.w);
  o.z = pack2bf(s1.x, s1.y);
  o.w = pack2bf(s1.z, s1.w);
  *(uint4*)(embbf + ((size_t)b * 2048 + m) * 128 + j) = o;
}

// neweT[b][i][m] = bf16(sum_{hg=0..7} part2bf[hg][b][i][m]); zero for m>=2000.
__global__ void k_cvt_red(const u16* __restrict__ part2, u16* __restrict__ neweT) {
  const int tid = blockIdx.x * 256 + threadIdx.x;  // 65,536
  const size_t f0 = (size_t)tid * 8;
  const int m0 = (int)(f0 & 2047);
  uint4 o;
  if (m0 >= Ev) {
    o = make_uint4(0, 0, 0, 0);
  } else {
    float s[8] = {0.f, 0.f, 0.f, 0.f, 0.f, 0.f, 0.f, 0.f};
#pragma unroll
    for (int hg = 0; hg < 8; ++hg) {
      uint4 v = *(const uint4*)(part2 + (size_t)hg * 524288 + f0);
      u32 wv[4] = {v.x, v.y, v.z, v.w};
#pragma unroll
      for (int q = 0; q < 4; ++q) {
        s[2 * q]     += __uint_as_float(wv[q] << 16);
        s[2 * q + 1] += __uint_as_float(wv[q] & 0xffff0000u);
      }
    }
    o.x = pack2bf(s[0], s[1]);
    o.y = pack2bf(s[2], s[3]);
    o.z = pack2bf(s[4], s[5]);
    o.w = pack2bf(s[6], s[7]);
  }
  *(uint4*)(neweT + f0) = o;
}

// out[b,n,i] = (sum_{kc=0..7} part3[kc][b,n,i] + ns) / (1 + sum_kc nrmp[kc][b,n])
__global__ void k_epi_red(const float* __restrict__ part3, const float* __restrict__ nrmp,
                          const float* __restrict__ ns, float* __restrict__ out) {
  const int tid = blockIdx.x * 256 + threadIdx.x;  // 64,000
  const size_t f0 = (size_t)tid * 4;
  const int row = (int)(f0 >> 7);  // b*1000+n
  const f32x4* p = (const f32x4*)(part3 + f0);
  f32x4 s = {0.f, 0.f, 0.f, 0.f};
#pragma unroll
  for (int kc = 0; kc < 8; ++kc) s += p[(size_t)kc * 64000];
  float nm = 1.0f;
#pragma unroll
  for (int kc = 0; kc < 8; ++kc) nm += nrmp[(size_t)kc * 2000 + row];
  f32x4 nsv = *(const f32x4*)(ns + f0);
  *(f32x4*)(out + f0) = (s + nsv) * (1.0f / nm);
}

// v12: SINGLE-buffer wave-private staging -> 37KB LDS -> 4 blocks/CU (2x TLP).
// Per h: vmcnt(0) [prev STAGE done] -> 8 ds_read -> lgkmcnt(0) [slice reads
// complete, safe to overwrite] -> issue STAGE(h+1) -> 32 MFMA + fold (hide
// staging latency). Per-wave counters keep waves fully decoupled; no barriers
// in loop. part2bf[hg][b][i][m] (hg = XCD). Grid 512 flat, 256 thr.
__launch_bounds__(256, 2)
__global__ void k_edge_mix(const float* __restrict__ ev, const u16* __restrict__ embbf,
                           const u16* __restrict__ enbf, u16* __restrict__ part2) {
  __shared__ u16 APL[4][4096];    // [wave][8KB slice], XOR-swizzled rows
  __shared__ float EVL[64 * 20];  // ev slice [64 m][16 h], stride 20
  const int id = blockIdx.x;
  const int hgrp = id & 7;        // XCD affinity
  const int rest = id >> 3;
  const int mt = rest & 31;
  const int b = rest >> 5;
  const int h0 = hgrp * 16;
  const int t = threadIdx.x;
  const int lane = t & 63;
  const int w = t >> 6;
  const int row16 = lane & 15;
  const int kg = lane >> 4;
  const int mbase = mt * 64;

  // stage ev slice once (guarded: pad rows -> 0, which zeroes their pers)
  if (t < 64) {
    const int ml = mbase + t;
    const float* src = ev + ((size_t)b * Ev + ml) * Hv + h0;
    const f32x4 z = {0.f, 0.f, 0.f, 0.f};
#pragma unroll
    for (int q = 0; q < 4; ++q) {
      f32x4 v = (ml < Ev) ? *(const f32x4*)(src + q * 4) : z;
      *(f32x4*)&EVL[t * 20 + q * 4] = v;
    }
  }

  // B-frags: direct bf16 loads from padded embbf [b][2048][128]
  bf16x8 bfrag[4][4];
  {
    const u16* ebase = embbf + ((size_t)b * 2048 + mbase) * 128;
#pragma unroll
    for (int mf = 0; mf < 4; ++mf) {
      const u16* rp = ebase + (size_t)(mf * 16 + row16) * 128;
#pragma unroll
      for (int kk = 0; kk < 4; ++kk)
        bfrag[mf][kk] = *(const bf16x8*)(rp + kk * 32 + kg * 8);
    }
  }

  // wave-private STAGE: this wave's 32 rows (8KB) of plane h into APL[w]
  auto STAGE = [&](int h) {
    const char* plane = (const char*)(enbf + (size_t)h * 16384) + (size_t)w * 8192;
    char* dst = (char*)&APL[w][0];
#pragma unroll
    for (int it = 0; it < 8; ++it) {
      const int r = it * 4 + (lane >> 4);       // row in slice 0..31
      const int inner = (lane & 15) << 4;       // byte col
      const int srcb = r * 256 + (inner ^ ((r & 7) << 4));
      gload_lds16(plane + srcb, dst + it * 1024);
    }
  };

  const f32x4 zero4 = {0.f, 0.f, 0.f, 0.f};
  f32x4 pers[2][4];
#pragma unroll
  for (int fi = 0; fi < 2; ++fi)
#pragma unroll
    for (int mf = 0; mf < 4; ++mf) pers[fi][mf] = zero4;

  const int xorv = (row16 & 7) << 4;

  STAGE(h0);
  __syncthreads();  // EVL visibility only (one barrier total)

#pragma unroll 1
  for (int hh = 0; hh < 16; ++hh) {
    asm volatile("s_waitcnt vmcnt(0)" ::: "memory");  // slice hh landed
    __builtin_amdgcn_sched_barrier(0);
    const char* sl = (const char*)&APL[w][0];
    bf16x8 a[2][4];
#pragma unroll
    for (int fi = 0; fi < 2; ++fi) {
      const int rs = fi * 16 + row16;
#pragma unroll
      for (int kk = 0; kk < 4; ++kk)
        a[fi][kk] = *(const bf16x8*)(sl + rs * 256 + ((kk * 64 + kg * 16) ^ xorv));
    }
    if (hh + 1 < 16) {
      asm volatile("s_waitcnt lgkmcnt(0)" ::: "memory");  // ds_reads done -> safe overwrite
      __builtin_amdgcn_sched_barrier(0);
      STAGE(h0 + hh + 1);  // flies while we do MFMA below
    }
    f32x4 q[2][4];
#pragma unroll
    for (int fi = 0; fi < 2; ++fi)
#pragma unroll
      for (int mf = 0; mf < 4; ++mf)
        q[fi][mf] = __builtin_amdgcn_mfma_f32_16x16x32_bf16(a[fi][0], bfrag[mf][0], zero4, 0, 0, 0);
#pragma unroll
    for (int kk = 1; kk < 4; ++kk)
#pragma unroll
      for (int fi = 0; fi < 2; ++fi)
#pragma unroll
        for (int mf = 0; mf < 4; ++mf)
          q[fi][mf] = __builtin_amdgcn_mfma_f32_16x16x32_bf16(a[fi][kk], bfrag[mf][kk], q[fi][mf], 0, 0, 0);
    float evv[4];
#pragma unroll
    for (int mf = 0; mf < 4; ++mf)
      evv[mf] = EVL[(mf * 16 + row16) * 20 + hh];
#pragma unroll
    for (int fi = 0; fi < 2; ++fi)
#pragma unroll
      for (int mf = 0; mf < 4; ++mf)
        pers[fi][mf] += evv[mf] * q[fi][mf];
  }

  // bf16 stores into this hgroup's private slice (cols >=2000 are zero via ev guard)
  u16* slice = part2 + (size_t)hgrp * (2 * 128 * 2048);
#pragma unroll
  for (int fi = 0; fi < 2; ++fi) {
#pragma unroll
    for (int mf = 0; mf < 4; ++mf) {
      const int ml = mbase + mf * 16 + row16;
#pragma unroll
      for (int r = 0; r < 4; ++r) {
        const int irow = w * 32 + fi * 16 + kg * 4 + r;
        slice[((size_t)b * 128 + irow) * 2048 + ml] = cvt1bf(pers[fi][mf][r]);
      }
    }
  }
}

extern "C" void kernel_launch(void* const* d_in, const int* in_sizes, int n_in,
                              void* d_out, int out_size, void* d_ws, size_t ws_size,
                              hipStream_t stream) {
  const float* ns  = (const float*)d_in[0];  // node_state  [B][N][H]
  const float* ev  = (const float*)d_in[1];  // edge_vec    [B][E][H]
  const float* n2e = (const float*)d_in[2];  // node2edge   [B][E][N]
  const float* e2n = (const float*)d_in[3];  // edge2node   [B][N][E]
  const float* en  = (const float*)d_in[4];  // edge_network[H][H][H]
  float* out = (float*)d_out;

  char* ws = (char*)d_ws;
  float* part1 = (float*)(ws);               // [4][2][2000][128] f32, 8,192,000
  u16*   part2 = (u16*)  (ws + 8192000);     // [8][2][128][2048] bf16, 8,388,608
  float* part3 = (float*)(ws + 16580608);    // [8][2][1000][128] f32, 8,192,000
  float* nrmp  = (float*)(ws + 24772608);    // [8][2][1000] f32, 64,000 (+pad)
  u16*   embbf = (u16*)  (ws + 24838144);    // [2][2048][128] bf16, 1,048,576 (padded)
  u16*   enbf  = (u16*)  (ws + 25886720);    // [128][128][128] bf16, 4,194,304
  u16*   nsT   = (u16*)  (ws + 30081024);    // [2][128][1024] bf16, 524,288
  u16*   neweT = (u16*)  (ws + 30605312);    // [2][128][2048] bf16, 1,048,576

  k_prep<<<dim3(1280), dim3(256), 0, stream>>>(en, enbf, ns, nsT);
  // part1[kc] = n2e @ nsT  (M=2000, K=1000, split-K x4, 2 chunks/block)
  k_gemm_flat<2000, 1000, 1024, 4, 2, 32, false><<<dim3(256), dim3(256), 0, stream>>>(n2e, nsT, part1, nullptr);
  k_reduce_emb<<<dim3(250), dim3(256), 0, stream>>>(part1, embbf);
  k_edge_mix<<<dim3(512), dim3(256), 0, stream>>>(ev, embbf, enbf, part2);
  k_cvt_red<<<dim3(256), dim3(256), 0, stream>>>(part2, neweT);
  // part3[kc] = e2n @ neweT  (M=1000, K=2000, split-K x8, 2 chunks/block) + rowsum partials
  k_gemm_flat<1000, 2000, 2048, 8, 2, 16, true><<<dim3(256), dim3(256), 0, stream>>>(e2n, neweT, part3, nrmp);
  k_epi_red<<<dim3(250), dim3(256), 0, stream>>>(part3, nrmp, ns, out);
}